// Round 10
// baseline (234.939 us; speedup 1.0000x reference)
//
#include <hip/hip_runtime.h>
#include <hip/hip_bf16.h>
#include <math.h>

typedef __hip_bfloat16 bf16;

__device__ __forceinline__ float b2f(bf16 v) { return __bfloat162float(v); }
__device__ __forceinline__ bf16  f2b(float v) { return __float2bfloat16(v); }

#define LOG2E 1.44269504088896340736f

template<int F32>
__device__ __forceinline__ float ldf(const void* p, int i) {
    return F32 ? ((const float*)p)[i] : b2f(((const bf16*)p)[i]);
}
// load x[2s], x[2s+1] as one dword (bf16) or dwordx2 (f32)
template<int F32>
__device__ __forceinline__ void ldx(const void* x, int s, float& x0, float& x1) {
    if (F32) { float2 v = ((const float2*)x)[s]; x0 = v.x; x1 = v.y; }
    else {
        unsigned u = ((const unsigned*)x)[s];
        x0 = __uint_as_float((u & 0xFFFFu) << 16);
        x1 = __uint_as_float(u & 0xFFFF0000u);
    }
}
// f32 -> bf16 bits (RNE), returned in HIGH 16 bits
__device__ __forceinline__ unsigned f2b_hi(float f) {
    unsigned u = __float_as_uint(f);
    u += 0x7FFFu + ((u >> 16) & 1u);
    return u & 0xFFFF0000u;
}
// CSR record: P4 -> 4B (attr_hi16 | src16, needs N<=65536); else 8B (src, attr_f32bits)
template<int P4>
__device__ __forceinline__ void ldrec(const void* csr, int k, int& s, float& a) {
    if (P4) {
        unsigned u = ((const unsigned*)csr)[k];
        s = (int)(u & 0xFFFFu);
        a = __uint_as_float(u & 0xFFFF0000u);
    } else {
        uint2 r = ((const uint2*)csr)[k];
        s = (int)r.x;
        a = __uint_as_float(r.y);
    }
}
__device__ __forceinline__ float sclamp(float v, float lim) {
    return fminf(fmaxf(v, -lim), lim);
}
// VALU-only sum over each 16-lane row
template<int CTRL>
__device__ __forceinline__ float dpp_add(float v) {
    int t = __builtin_amdgcn_update_dpp(0, __float_as_int(v), CTRL, 0xF, 0xF, true);
    return v + __int_as_float(t);
}
__device__ __forceinline__ float red16(float v) {
    v = dpp_add<0xB1>(v);    // quad_perm [1,0,3,2]
    v = dpp_add<0x4E>(v);    // quad_perm [2,3,0,1]
    v = dpp_add<0x124>(v);   // row_ror:4
    v = dpp_add<0x128>(v);   // row_ror:8
    return v;
}

#define NEG_SLOPE 0.2f
#define LN_EPS 1e-5f
#define SCAN_TILE 1024
#define ACHUNK 4096     // edges per bucket-bin block

__device__ __forceinline__ int ld_idx(const int* ei, long long pos, int is64, int N) {
    int v = is64 ? ei[2 * pos] : ei[pos];
    return min(max(v, 0), N - 1);
}
__device__ __forceinline__ int calc_is64(const int* ei) {
    int hi = 0, nz = 0;
    #pragma unroll
    for (int i = 0; i < 8; ++i) { hi |= ei[2 * i + 1]; nz |= ei[2 * i]; }
    return (hi == 0 && nz != 0) ? 1 : 0;
}

// ================= bucketed CSR build (N <= 65536): all scatter in LDS =================

__global__ __launch_bounds__(256) void histb_kernel(const int* __restrict__ ei,
                                                    const unsigned short* __restrict__ xu,
                                                    int E, int N, int* __restrict__ flags,
                                                    int* __restrict__ bcnt) {
    __shared__ int c[256];
    int tid = threadIdx.x;
    c[tid] = 0;
    int is64 = calc_is64(ei);
    if (blockIdx.x == 0 && tid == 0) {
        flags[0] = is64;
        int pl = 0;
        for (int i = 0; i < 32; ++i) {
            unsigned ex = (xu[2 * i] >> 7) & 0xFF;
            if (ex >= 100 && ex <= 140) pl++;
        }
        flags[1] = (pl >= 24) ? 0 : 1;   // 1 = float tensors are fp32
    }
    __syncthreads();
    int i0 = blockIdx.x * ACHUNK;
    int iend = min(i0 + ACHUNK, E);
    for (int i = i0 + tid; i < iend; i += 256)
        atomicAdd(&c[ld_idx(ei, (long long)E + i, is64, N) >> 8], 1);
    __syncthreads();
    if (c[tid]) atomicAdd(&bcnt[tid], c[tid]);
}

__global__ void scanb_kernel(const int* __restrict__ bcnt, int* __restrict__ bbase,
                             int* __restrict__ bcursor, int* __restrict__ rowptr,
                             int N, int E) {
    __shared__ int s[256];
    int tid = threadIdx.x;
    int v = bcnt[tid];
    s[tid] = v;
    __syncthreads();
    for (int off = 1; off < 256; off <<= 1) {
        int u = (tid >= off) ? s[tid - off] : 0;
        __syncthreads();
        s[tid] += u;
        __syncthreads();
    }
    int excl = s[tid] - v;
    bbase[tid] = excl;
    bcursor[tid] = excl;
    if (tid == 255) { bbase[256] = s[255]; rowptr[N] = E; }
}

template<int F32>
__device__ void bina_body(const int* __restrict__ ei, const void* __restrict__ attr,
                          int E, int N, int is64, int* __restrict__ bcursor,
                          uint2* __restrict__ binned) {
    __shared__ int cnt[256], incl[256], cur[256];
    __shared__ uint2 stage[ACHUNK];   // 32 KB
    int tid = threadIdx.x;
    cnt[tid] = 0;
    __syncthreads();
    int i0 = blockIdx.x * ACHUNK;
    int iend = min(i0 + ACHUNK, E);
    for (int i = i0 + tid; i < iend; i += 256)
        atomicAdd(&cnt[ld_idx(ei, (long long)E + i, is64, N) >> 8], 1);
    __syncthreads();
    incl[tid] = cnt[tid];
    __syncthreads();
    for (int off = 1; off < 256; off <<= 1) {
        int u = (tid >= off) ? incl[tid - off] : 0;
        __syncthreads();
        incl[tid] += u;
        __syncthreads();
    }
    cur[tid] = incl[tid] - cnt[tid];
    __syncthreads();
    for (int i = i0 + tid; i < iend; i += 256) {
        int d = ld_idx(ei, (long long)E + i, is64, N);
        int s = ld_idx(ei, (long long)i, is64, N);
        float a = ldf<F32>(attr, i);
        int p = atomicAdd(&cur[d >> 8], 1);
        stage[p] = make_uint2((unsigned)s | ((unsigned)(d & 255) << 16), f2b_hi(a));
    }
    __syncthreads();
    int c = cnt[tid];
    if (c > 0) {
        int start = incl[tid] - c;
        int g = atomicAdd(&bcursor[tid], c);
        for (int j = 0; j < c; ++j) binned[g + j] = stage[start + j];
    }
}

__global__ __launch_bounds__(256) void bina_kernel(const int* __restrict__ ei,
                                                   const void* __restrict__ attr,
                                                   int E, int N, const int* __restrict__ flags,
                                                   int* __restrict__ bcursor,
                                                   uint2* __restrict__ binned) {
    if (flags[1]) bina_body<1>(ei, attr, E, N, flags[0], bcursor, binned);
    else          bina_body<0>(ei, attr, E, N, flags[0], bcursor, binned);
}

__global__ __launch_bounds__(256) void passb_kernel(const uint2* __restrict__ binned,
                                                    const int* __restrict__ bbase,
                                                    int* __restrict__ rowptr,
                                                    unsigned* __restrict__ csr, int N) {
    __shared__ int nc[256], incl[256], cur[256];
    int b = blockIdx.x, tid = threadIdx.x;
    int base = bbase[b], cntb = bbase[b + 1] - base;
    nc[tid] = 0;
    __syncthreads();
    for (int i = tid; i < cntb; i += 256)
        atomicAdd(&nc[(binned[base + i].x >> 16) & 255], 1);
    __syncthreads();
    incl[tid] = nc[tid];
    __syncthreads();
    for (int off = 1; off < 256; off <<= 1) {
        int u = (tid >= off) ? incl[tid - off] : 0;
        __syncthreads();
        incl[tid] += u;
        __syncthreads();
    }
    int excl = incl[tid] - nc[tid];
    int node = (b << 8) + tid;
    if (node < N) rowptr[node] = base + excl;
    cur[tid] = excl;
    __syncthreads();
    for (int i = tid; i < cntb; i += 256) {
        uint2 r = binned[base + i];
        int p = atomicAdd(&cur[(r.x >> 16) & 255], 1);
        csr[base + p] = r.y | (r.x & 0xFFFFu);
    }
}

// ================= fallback CSR build (N > 65536) =================

__global__ void hist_kernel(const int* __restrict__ ei, const unsigned short* __restrict__ xu,
                            int E, int N, int* __restrict__ flags, int* __restrict__ cnt) {
    int is64 = calc_is64(ei);
    if (blockIdx.x == 0 && threadIdx.x == 0) {
        flags[0] = is64;
        int pl = 0;
        for (int i = 0; i < 32; ++i) {
            unsigned ex = (xu[2 * i] >> 7) & 0xFF;
            if (ex >= 100 && ex <= 140) pl++;
        }
        flags[1] = (pl >= 24) ? 0 : 1;
    }
    int e = blockIdx.x * blockDim.x + threadIdx.x;
    if (e >= E) return;
    atomicAdd(&cnt[ld_idx(ei, (long long)E + e, is64, N)], 1);
}

__global__ __launch_bounds__(256) void scan_partial(const int* __restrict__ cnt,
                                                    int* __restrict__ bsum, int N) {
    __shared__ int wsum[4];
    int b = blockIdx.x, tid = threadIdx.x;
    int base = b * SCAN_TILE + tid * 4;
    int4 v = make_int4(0, 0, 0, 0);
    if (base + 3 < N) v = *(const int4*)(cnt + base);
    else {
        if (base + 0 < N) v.x = cnt[base + 0];
        if (base + 1 < N) v.y = cnt[base + 1];
        if (base + 2 < N) v.z = cnt[base + 2];
    }
    int s = v.x + v.y + v.z + v.w;
    #pragma unroll
    for (int off = 1; off < 64; off <<= 1) s += __shfl_xor(s, off);
    if ((tid & 63) == 0) wsum[tid >> 6] = s;
    __syncthreads();
    if (tid == 0) bsum[b] = wsum[0] + wsum[1] + wsum[2] + wsum[3];
}

__global__ __launch_bounds__(256) void scan_final(int* __restrict__ cnt, int* __restrict__ rowptr,
                                                  const int* __restrict__ bsum, int N, int B) {
    __shared__ int tsum[256];
    __shared__ int bpre[256];
    int b = blockIdx.x, tid = threadIdx.x;
    bpre[tid] = (tid < B) ? bsum[tid] : 0;
    int base = b * SCAN_TILE + tid * 4;
    int4 v = make_int4(0, 0, 0, 0);
    if (base + 3 < N) v = *(const int4*)(cnt + base);
    else {
        if (base + 0 < N) v.x = cnt[base + 0];
        if (base + 1 < N) v.y = cnt[base + 1];
        if (base + 2 < N) v.z = cnt[base + 2];
    }
    tsum[tid] = v.x + v.y + v.z + v.w;
    __syncthreads();
    for (int off = 1; off < 256; off <<= 1) {
        int t = (tid >= off) ? tsum[tid - off] : 0;
        int u = (tid >= off) ? bpre[tid - off] : 0;
        __syncthreads();
        tsum[tid] += t;
        bpre[tid] += u;
        __syncthreads();
    }
    int blockpre = (b == 0) ? 0 : bpre[b - 1];
    int o0 = blockpre + ((tid == 0) ? 0 : tsum[tid - 1]);
    int o1 = o0 + v.x, o2 = o1 + v.y, o3 = o2 + v.z;
    if (base + 3 < N) {
        int4 o = make_int4(o0, o1, o2, o3);
        *(int4*)(rowptr + base) = o;
        *(int4*)(cnt + base) = o;
    } else {
        if (base + 0 < N) { rowptr[base + 0] = o0; cnt[base + 0] = o0; }
        if (base + 1 < N) { rowptr[base + 1] = o1; cnt[base + 1] = o1; }
        if (base + 2 < N) { rowptr[base + 2] = o2; cnt[base + 2] = o2; }
    }
    if (b == 0 && tid == 255) rowptr[N] = bpre[255];
}

template<int F32>
__device__ void scatter_body(const int* __restrict__ ei, const void* __restrict__ attr,
                             int E, int N, int is64, int* __restrict__ cursor,
                             uint2* __restrict__ csr) {
    int e = blockIdx.x * blockDim.x + threadIdx.x;
    if (e >= E) return;
    int d = ld_idx(ei, (long long)E + e, is64, N);
    int s = ld_idx(ei, (long long)e, is64, N);
    float av = ldf<F32>(attr, e);
    int pos = atomicAdd(&cursor[d], 1);
    csr[pos] = make_uint2((unsigned)s, __float_as_uint(av));
}

__global__ void scatter_kernel(const int* __restrict__ ei, const void* __restrict__ attr,
                               int E, int N, const int* __restrict__ flags,
                               int* __restrict__ cursor, uint2* __restrict__ csr) {
    if (flags[1]) scatter_body<1>(ei, attr, E, N, flags[0], cursor, csr);
    else          scatter_body<0>(ei, attr, E, N, flags[0], cursor, csr);
}

// ================= Layer-1 aggregation =================
// exp2-domain: all logit-path constants premultiplied by LOG2E; exp -> native v_exp.

template<int F32, int P4>
__device__ void agg1_body(
    const int* __restrict__ rowptr, const void* __restrict__ csr,
    const void* __restrict__ x,
    const void* W1l, const void* b1l, const void* W1r, const void* b1r,
    const void* We1, const void* att1, const void* bias1, const void* g1v, const void* beta1,
    bf16* __restrict__ hout, int N) {
    int w0 = __builtin_amdgcn_readfirstlane((blockIdx.x * blockDim.x + threadIdx.x) >> 6);
    int NW = (gridDim.x * blockDim.x) >> 6;
    int lane = threadIdx.x & 63;
    int h = lane >> 4, q = lane & 15;
    int ja = h * 32 + q, jb = ja + 16;

    float wlaA = ldf<F32>(W1l, ja),      wlaB = ldf<F32>(W1l, jb);
    float wlbA = ldf<F32>(W1l, 128 + ja), wlbB = ldf<F32>(W1l, 128 + jb);
    float wraA = ldf<F32>(W1r, ja),      wraB = ldf<F32>(W1r, jb);
    float wrbA = ldf<F32>(W1r, 128 + ja), wrbB = ldf<F32>(W1r, 128 + jb);
    float blA = ldf<F32>(b1l, ja), blB = ldf<F32>(b1l, jb);
    float brA = ldf<F32>(b1r, ja), brB = ldf<F32>(b1r, jb);
    float weA = ldf<F32>(We1, ja), weB = ldf<F32>(We1, jb);
    float atA = ldf<F32>(att1, ja), atB = ldf<F32>(att1, jb);
    float aa4A = (0.4f * LOG2E) * atA, aa4B = (0.4f * LOG2E) * atB;
    float blbrA = blA + brA, blbrB = blB + brB;
    const float c6 = 0.6f * LOG2E;
    float P0 = c6 * red16(atA * wlaA + atB * wlaB);
    float P1 = c6 * red16(atA * wlbA + atB * wlbB);
    float Pw = c6 * red16(atA * weA + atB * weB);
    float Q0 = c6 * red16(atA * wraA + atB * wraB);
    float Q1 = c6 * red16(atA * wrbA + atB * wrbB);
    float Qc = c6 * red16(atA * blbrA + atB * blbrB);
    float biasA = ldf<F32>(bias1, q), biasB = ldf<F32>(bias1, q + 16);
    float gA = ldf<F32>(g1v, q), gB = ldf<F32>(g1v, q + 16);
    float beA = ldf<F32>(beta1, q), beB = ldf<F32>(beta1, q + 16);

    for (int n = w0; n < N; n += NW) {
        int beg = rowptr[n], end = rowptr[n + 1];
        float xd0, xd1;
        ldx<F32>(x, n, xd0, xd1);
        float cA = fmaf(xd0, wraA, fmaf(xd1, wrbA, blbrA));
        float cB = fmaf(xd0, wraB, fmaf(xd1, wrbB, blbrB));
        float Kn = fmaf(xd0, Q0, fmaf(xd1, Q1, Qc));
        float S = 0.f, Sx0 = 0.f, Sx1 = 0.f;

        auto edge = [&](float xs0, float xs1, float a) {
            float zA = fmaf(xs0, wlaA, fmaf(xs1, wlbA, fmaf(a, weA, cA)));
            float zB = fmaf(xs0, wlaB, fmaf(xs1, wlbB, fmaf(a, weB, cB)));
            float pabs = red16(fmaf(fabsf(zA), aa4A, fabsf(zB) * aa4B));
            float p = sclamp(fmaf(xs0, P0, fmaf(xs1, P1, fmaf(a, Pw, Kn))) + pabs, 86.f);
            float e = __builtin_exp2f(p);       // exp2-domain: single v_exp
            S += e;
            Sx0 = fmaf(e, xs0, Sx0);
            Sx1 = fmaf(e, xs1, Sx1);
        };

        int k = beg;
        for (; k + 8 <= end; k += 8) {          // 8x batch: all gathers in flight
            int ss[8]; float aa[8], xx0[8], xx1[8];
            #pragma unroll
            for (int j = 0; j < 8; ++j) ldrec<P4>(csr, k + j, ss[j], aa[j]);
            #pragma unroll
            for (int j = 0; j < 8; ++j) ldx<F32>(x, ss[j], xx0[j], xx1[j]);
            #pragma unroll
            for (int j = 0; j < 8; ++j) edge(xx0[j], xx1[j], aa[j]);
        }
        for (; k < end; ++k) {
            int s0; float a0;
            ldrec<P4>(csr, k, s0, a0);
            float p0, p1;
            ldx<F32>(x, s0, p0, p1);
            edge(p0, p1, a0);
        }

        float inv = 1.0f / (S + 1e-16f);
        float R = S * inv, U0 = Sx0 * inv, U1 = Sx1 * inv;
        float outA = fmaf(U0, wlaA, fmaf(U1, wlbA, R * blA));
        float outB = fmaf(U0, wlaB, fmaf(U1, wlbB, R * blB));
        outA += __shfl_xor(outA, 16); outA += __shfl_xor(outA, 32);
        outB += __shfl_xor(outB, 16); outB += __shfl_xor(outB, 32);
        float valA = fmaf(0.25f, outA, biasA);
        float valB = fmaf(0.25f, outB, biasB);
        float mu = red16(valA + valB) * (1.f / 32.f);
        float dA = valA - mu, dB = valB - mu;
        float var = red16(dA * dA + dB * dB) * (1.f / 32.f);
        float rs = rsqrtf(var + LN_EPS);
        float yA = fmaf(dA * rs, gA, beA);
        float yB = fmaf(dB * rs, gB, beB);
        float hA = yA > 0.f ? yA : expm1f(yA);
        float hB = yB > 0.f ? yB : expm1f(yB);
        if (lane < 16) {
            hout[n * 32 + q]      = f2b(hA);
            hout[n * 32 + 16 + q] = f2b(hB);
        }
    }
}

template<int P4>
__global__ __launch_bounds__(256) void agg1_kernel(
    const int* __restrict__ flags,
    const int* __restrict__ rowptr, const void* __restrict__ csr,
    const void* __restrict__ x,
    const void* W1l, const void* b1l, const void* W1r, const void* b1r,
    const void* We1, const void* att1, const void* bias1, const void* g1v, const void* beta1,
    bf16* __restrict__ hout, int N) {
    if (flags[1]) agg1_body<1, P4>(rowptr, csr, x, W1l, b1l, W1r, b1r,
                                   We1, att1, bias1, g1v, beta1, hout, N);
    else          agg1_body<0, P4>(rowptr, csr, x, W1l, b1l, W1r, b1r,
                                   We1, att1, bias1, g1v, beta1, hout, N);
}

// ================= Layer-2 node transform, in-place over hbuf =================

template<int F32>
__device__ void node2_body(bf16* __restrict__ hbuf, float* wl, float* wr,
                           const void* W2l, const void* b2l, const void* W2r, const void* b2r,
                           int N) {
    __shared__ float bl[16], br[16];
    int tid = threadIdx.x;
    for (int i = tid; i < 512; i += 256) { wl[i] = ldf<F32>(W2l, i); wr[i] = ldf<F32>(W2r, i); }
    if (tid < 16) { bl[tid] = ldf<F32>(b2l, tid); br[tid] = ldf<F32>(b2r, tid); }
    __syncthreads();
    int n = blockIdx.x * blockDim.x + tid;
    if (n >= N) return;
    float hv[32];
    #pragma unroll
    for (int c = 0; c < 32; ++c) hv[c] = b2f(hbuf[n * 32 + c]);
    float accl[16], accr[16];
    #pragma unroll
    for (int o = 0; o < 16; ++o) { accl[o] = bl[o]; accr[o] = br[o]; }
    #pragma unroll
    for (int c = 0; c < 32; ++c) {
        #pragma unroll
        for (int o = 0; o < 16; ++o) {
            accl[o] = fmaf(hv[c], wl[c * 16 + o], accl[o]);
            accr[o] = fmaf(hv[c], wr[c * 16 + o], accr[o]);
        }
    }
    #pragma unroll
    for (int o = 0; o < 16; ++o) {
        hbuf[n * 32 + o]      = f2b(accl[o]);   // h2l
        hbuf[n * 32 + 16 + o] = f2b(accr[o]);   // h2r
    }
}

__global__ __launch_bounds__(256) void node2_kernel(
    const int* __restrict__ flags, bf16* __restrict__ hbuf,
    const void* W2l, const void* b2l, const void* W2r, const void* b2r, int N) {
    __shared__ float wl[512], wr[512];
    if (flags[1]) node2_body<1>(hbuf, wl, wr, W2l, b2l, W2r, b2r, N);
    else          node2_body<0>(hbuf, wl, wr, W2l, b2l, W2r, b2r, N);
}

// ================= Layer-2 aggregation =================

template<int F32, int P4>
__device__ void agg2_body(
    const int* __restrict__ rowptr, const void* __restrict__ csr,
    const bf16* __restrict__ h2,
    const void* We2, const void* att2, const void* bias2, const void* g2v, const void* beta2,
    void* __restrict__ out, int N) {
    int w0 = __builtin_amdgcn_readfirstlane((blockIdx.x * blockDim.x + threadIdx.x) >> 6);
    int NW = (gridDim.x * blockDim.x) >> 6;
    int lane = threadIdx.x & 63;
    int g = lane >> 4, t = lane & 15;

    float we = ldf<F32>(We2, t), at = LOG2E * ldf<F32>(att2, t);   // exp2-domain
    float bia = ldf<F32>(bias2, t), gg = ldf<F32>(g2v, t), bb = ldf<F32>(beta2, t);

    for (int n = w0; n < N; n += NW) {
        int beg = rowptr[n], end = rowptr[n + 1];
        float xr = b2f(h2[n * 32 + 16 + t]);   // h2r

        float S = 0.f, A = 0.f;
        auto edge = [&](float v, float a) {
            float m = fmaf(a, we, v + xr);
            m = fmaxf(m, NEG_SLOPE * m);
            float p = sclamp(red16(m * at), 86.f);
            float e = __builtin_exp2f(p);
            S += e;
            A = fmaf(e, v, A);
        };
        int k = beg + g;
        for (; k + 4 < end; k += 8) {
            int s0, s1; float a0, a1;
            ldrec<P4>(csr, k, s0, a0);
            ldrec<P4>(csr, k + 4, s1, a1);
            float v0 = b2f(h2[s0 * 32 + t]);
            float v1 = b2f(h2[s1 * 32 + t]);
            edge(v0, a0);
            edge(v1, a1);
        }
        if (k < end) {
            int s0; float a0;
            ldrec<P4>(csr, k, s0, a0);
            edge(b2f(h2[s0 * 32 + t]), a0);
        }
        S += __shfl_xor(S, 16); S += __shfl_xor(S, 32);
        A += __shfl_xor(A, 16); A += __shfl_xor(A, 32);
        float val = A / (S + 1e-16f) + bia;

        float mu = red16(val) * (1.f / 16.f);
        float d = val - mu;
        float var = red16(d * d) * (1.f / 16.f);
        float y = fmaf(d * rsqrtf(var + LN_EPS), gg, bb);
        if (lane < 16) {
            if (F32) ((float*)out)[n * 16 + t] = y;
            else     ((bf16*)out)[n * 16 + t] = f2b(y);
        }
    }
}

template<int P4>
__global__ __launch_bounds__(256) void agg2_kernel(
    const int* __restrict__ flags,
    const int* __restrict__ rowptr, const void* __restrict__ csr,
    const bf16* __restrict__ h2,
    const void* We2, const void* att2, const void* bias2, const void* g2v, const void* beta2,
    void* __restrict__ out, int N) {
    if (flags[1]) agg2_body<1, P4>(rowptr, csr, h2, We2, att2, bias2, g2v, beta2, out, N);
    else          agg2_body<0, P4>(rowptr, csr, h2, We2, att2, bias2, g2v, beta2, out, N);
}

// ================= host =================

static inline size_t align256(size_t x) { return (x + 255) & ~size_t(255); }

extern "C" void kernel_launch(void* const* d_in, const int* in_sizes, int n_in,
                              void* d_out, int out_size, void* d_ws, size_t ws_size,
                              hipStream_t stream) {
    const void* x     = d_in[0];
    const int*  ei    = (const int*)d_in[1];
    const void* eattr = d_in[2];
    const void* W1l   = d_in[3];
    const void* b1l   = d_in[4];
    const void* W1r   = d_in[5];
    const void* b1r   = d_in[6];
    const void* We1   = d_in[7];
    const void* att1  = d_in[8];
    const void* bias1 = d_in[9];
    const void* g1    = d_in[10];
    const void* beta1 = d_in[11];
    const void* W2l   = d_in[12];
    const void* b2l   = d_in[13];
    const void* W2r   = d_in[14];
    const void* b2r   = d_in[15];
    const void* We2   = d_in[16];
    const void* att2  = d_in[17];
    const void* bias2 = d_in[18];
    const void* g2    = d_in[19];
    const void* beta2 = d_in[20];

    const int N = in_sizes[0] / 2;   // x is (N,2)
    const int E = in_sizes[2];       // edge_attr is (E,1)
    const bool p4 = (N <= 65536);
    const int EB = (E + ACHUNK - 1) / ACHUNK;

    char* ws = (char*)d_ws;
    size_t off = 0;
    int* flags   = (int*)(ws + off); off += align256(sizeof(int) * 2);
    int* bcnt    = (int*)(ws + off); off += align256(sizeof(int) * 1024);
    int* bbase   = (int*)(ws + off); off += align256(sizeof(int) * 257);
    int* bcursor = (int*)(ws + off); off += align256(sizeof(int) * 256);
    int* rowptr  = (int*)(ws + off); off += align256(sizeof(int) * (size_t)(N + 1));
    void* csr    = (void*)(ws + off); off += align256((p4 ? 4u : 8u) * (size_t)E);
    char* big    = (ws + off);
    uint2* binned = (uint2*)big;
    int*   cnt    = (int*)big;
    bf16*  hbuf   = (bf16*)big;

    if (p4) {
        hipMemsetAsync(bcnt, 0, sizeof(int) * 256, stream);
        histb_kernel<<<EB, 256, 0, stream>>>(ei, (const unsigned short*)x, E, N, flags, bcnt);
        scanb_kernel<<<1, 256, 0, stream>>>(bcnt, bbase, bcursor, rowptr, N, E);
        bina_kernel<<<EB, 256, 0, stream>>>(ei, eattr, E, N, flags, bcursor, binned);
        passb_kernel<<<(N + 255) >> 8, 256, 0, stream>>>(binned, bbase, rowptr, (unsigned*)csr, N);
    } else {
        cnt = (int*)big;
        hbuf = (bf16*)(big + align256(sizeof(int) * (size_t)N));
        const int B = (N + SCAN_TILE - 1) / SCAN_TILE;
        hipMemsetAsync(cnt, 0, sizeof(int) * (size_t)N, stream);
        hist_kernel<<<(E + 255) / 256, 256, 0, stream>>>(ei, (const unsigned short*)x, E, N, flags, cnt);
        scan_partial<<<B, 256, 0, stream>>>(cnt, bcnt, N);
        scan_final<<<B, 256, 0, stream>>>(cnt, rowptr, bcnt, N, B);
        scatter_kernel<<<(E + 255) / 256, 256, 0, stream>>>(ei, eattr, E, N, flags, cnt, (uint2*)csr);
    }

    if (p4) agg1_kernel<1><<<3072, 256, 0, stream>>>(flags, rowptr, csr, x,
                                                     W1l, b1l, W1r, b1r, We1, att1,
                                                     bias1, g1, beta1, hbuf, N);
    else    agg1_kernel<0><<<3072, 256, 0, stream>>>(flags, rowptr, csr, x,
                                                     W1l, b1l, W1r, b1r, We1, att1,
                                                     bias1, g1, beta1, hbuf, N);

    node2_kernel<<<(N + 255) / 256, 256, 0, stream>>>(flags, hbuf, W2l, b2l, W2r, b2r, N);

    if (p4) agg2_kernel<1><<<3072, 256, 0, stream>>>(flags, rowptr, csr, hbuf,
                                                     We2, att2, bias2, g2, beta2, d_out, N);
    else    agg2_kernel<0><<<3072, 256, 0, stream>>>(flags, rowptr, csr, hbuf,
                                                     We2, att2, bias2, g2, beta2, d_out, N);
}

// Round 11
// 227.728 us; speedup vs baseline: 1.0317x; 1.0317x over previous
//
#include <hip/hip_runtime.h>
#include <hip/hip_bf16.h>
#include <math.h>

typedef __hip_bfloat16 bf16;

__device__ __forceinline__ float b2f(bf16 v) { return __bfloat162float(v); }
__device__ __forceinline__ bf16  f2b(float v) { return __float2bfloat16(v); }

#define LOG2E 1.44269504088896340736f

template<int F32>
__device__ __forceinline__ float ldf(const void* p, int i) {
    return F32 ? ((const float*)p)[i] : b2f(((const bf16*)p)[i]);
}
// load x[2s], x[2s+1] as one dword (bf16) or dwordx2 (f32)
template<int F32>
__device__ __forceinline__ void ldx(const void* x, int s, float& x0, float& x1) {
    if (F32) { float2 v = ((const float2*)x)[s]; x0 = v.x; x1 = v.y; }
    else {
        unsigned u = ((const unsigned*)x)[s];
        x0 = __uint_as_float((u & 0xFFFFu) << 16);
        x1 = __uint_as_float(u & 0xFFFF0000u);
    }
}
// f32 -> bf16 bits (RNE), returned in HIGH 16 bits
__device__ __forceinline__ unsigned f2b_hi(float f) {
    unsigned u = __float_as_uint(f);
    u += 0x7FFFu + ((u >> 16) & 1u);
    return u & 0xFFFF0000u;
}
// CSR record: P4 -> 4B (attr_hi16 | src16, needs N<=65536); else 8B (src, attr_f32bits)
template<int P4>
__device__ __forceinline__ void ldrec(const void* csr, int k, int& s, float& a) {
    if (P4) {
        unsigned u = ((const unsigned*)csr)[k];
        s = (int)(u & 0xFFFFu);
        a = __uint_as_float(u & 0xFFFF0000u);
    } else {
        uint2 r = ((const uint2*)csr)[k];
        s = (int)r.x;
        a = __uint_as_float(r.y);
    }
}
__device__ __forceinline__ float sclamp(float v, float lim) {
    return fminf(fmaxf(v, -lim), lim);
}
// VALU-only sum over each 16-lane row
template<int CTRL>
__device__ __forceinline__ float dpp_add(float v) {
    int t = __builtin_amdgcn_update_dpp(0, __float_as_int(v), CTRL, 0xF, 0xF, true);
    return v + __int_as_float(t);
}
__device__ __forceinline__ float red16(float v) {
    v = dpp_add<0xB1>(v);    // quad_perm [1,0,3,2]
    v = dpp_add<0x4E>(v);    // quad_perm [2,3,0,1]
    v = dpp_add<0x124>(v);   // row_ror:4
    v = dpp_add<0x128>(v);   // row_ror:8
    return v;
}

#define NEG_SLOPE 0.2f
#define LN_EPS 1e-5f
#define SCAN_TILE 1024
#define ACHUNK 4096     // edges per bucket-bin block

__device__ __forceinline__ int ld_idx(const int* ei, long long pos, int is64, int N) {
    int v = is64 ? ei[2 * pos] : ei[pos];
    return min(max(v, 0), N - 1);
}
__device__ __forceinline__ int calc_is64(const int* ei) {
    int hi = 0, nz = 0;
    #pragma unroll
    for (int i = 0; i < 8; ++i) { hi |= ei[2 * i + 1]; nz |= ei[2 * i]; }
    return (hi == 0 && nz != 0) ? 1 : 0;
}

// ================= bucketed CSR build (N <= 65536): all scatter in LDS =================

__global__ __launch_bounds__(256) void histb_kernel(const int* __restrict__ ei,
                                                    const unsigned short* __restrict__ xu,
                                                    int E, int N, int* __restrict__ flags,
                                                    int* __restrict__ bcnt) {
    __shared__ int c[256];
    int tid = threadIdx.x;
    c[tid] = 0;
    int is64 = calc_is64(ei);
    if (blockIdx.x == 0 && tid == 0) {
        flags[0] = is64;
        int pl = 0;
        for (int i = 0; i < 32; ++i) {
            unsigned ex = (xu[2 * i] >> 7) & 0xFF;
            if (ex >= 100 && ex <= 140) pl++;
        }
        flags[1] = (pl >= 24) ? 0 : 1;   // 1 = float tensors are fp32
    }
    __syncthreads();
    int i0 = blockIdx.x * ACHUNK;
    int iend = min(i0 + ACHUNK, E);
    for (int i = i0 + tid; i < iend; i += 256)
        atomicAdd(&c[ld_idx(ei, (long long)E + i, is64, N) >> 8], 1);
    __syncthreads();
    if (c[tid]) atomicAdd(&bcnt[tid], c[tid]);
}

__global__ void scanb_kernel(const int* __restrict__ bcnt, int* __restrict__ bbase,
                             int* __restrict__ bcursor, int* __restrict__ rowptr,
                             int N, int E) {
    __shared__ int s[256];
    int tid = threadIdx.x;
    int v = bcnt[tid];
    s[tid] = v;
    __syncthreads();
    for (int off = 1; off < 256; off <<= 1) {
        int u = (tid >= off) ? s[tid - off] : 0;
        __syncthreads();
        s[tid] += u;
        __syncthreads();
    }
    int excl = s[tid] - v;
    bbase[tid] = excl;
    bcursor[tid] = excl;
    if (tid == 255) { bbase[256] = s[255]; rowptr[N] = E; }
}

template<int F32>
__device__ void bina_body(const int* __restrict__ ei, const void* __restrict__ attr,
                          int E, int N, int is64, int* __restrict__ bcursor,
                          uint2* __restrict__ binned) {
    __shared__ int cnt[256], incl[256], cur[256];
    __shared__ uint2 stage[ACHUNK];   // 32 KB
    int tid = threadIdx.x;
    cnt[tid] = 0;
    __syncthreads();
    int i0 = blockIdx.x * ACHUNK;
    int iend = min(i0 + ACHUNK, E);
    for (int i = i0 + tid; i < iend; i += 256)
        atomicAdd(&cnt[ld_idx(ei, (long long)E + i, is64, N) >> 8], 1);
    __syncthreads();
    incl[tid] = cnt[tid];
    __syncthreads();
    for (int off = 1; off < 256; off <<= 1) {
        int u = (tid >= off) ? incl[tid - off] : 0;
        __syncthreads();
        incl[tid] += u;
        __syncthreads();
    }
    cur[tid] = incl[tid] - cnt[tid];
    __syncthreads();
    for (int i = i0 + tid; i < iend; i += 256) {
        int d = ld_idx(ei, (long long)E + i, is64, N);
        int s = ld_idx(ei, (long long)i, is64, N);
        float a = ldf<F32>(attr, i);
        int p = atomicAdd(&cur[d >> 8], 1);
        stage[p] = make_uint2((unsigned)s | ((unsigned)(d & 255) << 16), f2b_hi(a));
    }
    __syncthreads();
    int c = cnt[tid];
    if (c > 0) {
        int start = incl[tid] - c;
        int g = atomicAdd(&bcursor[tid], c);
        for (int j = 0; j < c; ++j) binned[g + j] = stage[start + j];
    }
}

__global__ __launch_bounds__(256) void bina_kernel(const int* __restrict__ ei,
                                                   const void* __restrict__ attr,
                                                   int E, int N, const int* __restrict__ flags,
                                                   int* __restrict__ bcursor,
                                                   uint2* __restrict__ binned) {
    if (flags[1]) bina_body<1>(ei, attr, E, N, flags[0], bcursor, binned);
    else          bina_body<0>(ei, attr, E, N, flags[0], bcursor, binned);
}

__global__ __launch_bounds__(256) void passb_kernel(const uint2* __restrict__ binned,
                                                    const int* __restrict__ bbase,
                                                    int* __restrict__ rowptr,
                                                    unsigned* __restrict__ csr, int N) {
    __shared__ int nc[256], incl[256], cur[256];
    int b = blockIdx.x, tid = threadIdx.x;
    int base = bbase[b], cntb = bbase[b + 1] - base;
    nc[tid] = 0;
    __syncthreads();
    for (int i = tid; i < cntb; i += 256)
        atomicAdd(&nc[(binned[base + i].x >> 16) & 255], 1);
    __syncthreads();
    incl[tid] = nc[tid];
    __syncthreads();
    for (int off = 1; off < 256; off <<= 1) {
        int u = (tid >= off) ? incl[tid - off] : 0;
        __syncthreads();
        incl[tid] += u;
        __syncthreads();
    }
    int excl = incl[tid] - nc[tid];
    int node = (b << 8) + tid;
    if (node < N) rowptr[node] = base + excl;
    cur[tid] = excl;
    __syncthreads();
    for (int i = tid; i < cntb; i += 256) {
        uint2 r = binned[base + i];
        int p = atomicAdd(&cur[(r.x >> 16) & 255], 1);
        csr[base + p] = r.y | (r.x & 0xFFFFu);
    }
}

// ================= fallback CSR build (N > 65536) =================

__global__ void hist_kernel(const int* __restrict__ ei, const unsigned short* __restrict__ xu,
                            int E, int N, int* __restrict__ flags, int* __restrict__ cnt) {
    int is64 = calc_is64(ei);
    if (blockIdx.x == 0 && threadIdx.x == 0) {
        flags[0] = is64;
        int pl = 0;
        for (int i = 0; i < 32; ++i) {
            unsigned ex = (xu[2 * i] >> 7) & 0xFF;
            if (ex >= 100 && ex <= 140) pl++;
        }
        flags[1] = (pl >= 24) ? 0 : 1;
    }
    int e = blockIdx.x * blockDim.x + threadIdx.x;
    if (e >= E) return;
    atomicAdd(&cnt[ld_idx(ei, (long long)E + e, is64, N)], 1);
}

__global__ __launch_bounds__(256) void scan_partial(const int* __restrict__ cnt,
                                                    int* __restrict__ bsum, int N) {
    __shared__ int wsum[4];
    int b = blockIdx.x, tid = threadIdx.x;
    int base = b * SCAN_TILE + tid * 4;
    int4 v = make_int4(0, 0, 0, 0);
    if (base + 3 < N) v = *(const int4*)(cnt + base);
    else {
        if (base + 0 < N) v.x = cnt[base + 0];
        if (base + 1 < N) v.y = cnt[base + 1];
        if (base + 2 < N) v.z = cnt[base + 2];
    }
    int s = v.x + v.y + v.z + v.w;
    #pragma unroll
    for (int off = 1; off < 64; off <<= 1) s += __shfl_xor(s, off);
    if ((tid & 63) == 0) wsum[tid >> 6] = s;
    __syncthreads();
    if (tid == 0) bsum[b] = wsum[0] + wsum[1] + wsum[2] + wsum[3];
}

__global__ __launch_bounds__(256) void scan_final(int* __restrict__ cnt, int* __restrict__ rowptr,
                                                  const int* __restrict__ bsum, int N, int B) {
    __shared__ int tsum[256];
    __shared__ int bpre[256];
    int b = blockIdx.x, tid = threadIdx.x;
    bpre[tid] = (tid < B) ? bsum[tid] : 0;
    int base = b * SCAN_TILE + tid * 4;
    int4 v = make_int4(0, 0, 0, 0);
    if (base + 3 < N) v = *(const int4*)(cnt + base);
    else {
        if (base + 0 < N) v.x = cnt[base + 0];
        if (base + 1 < N) v.y = cnt[base + 1];
        if (base + 2 < N) v.z = cnt[base + 2];
    }
    tsum[tid] = v.x + v.y + v.z + v.w;
    __syncthreads();
    for (int off = 1; off < 256; off <<= 1) {
        int t = (tid >= off) ? tsum[tid - off] : 0;
        int u = (tid >= off) ? bpre[tid - off] : 0;
        __syncthreads();
        tsum[tid] += t;
        bpre[tid] += u;
        __syncthreads();
    }
    int blockpre = (b == 0) ? 0 : bpre[b - 1];
    int o0 = blockpre + ((tid == 0) ? 0 : tsum[tid - 1]);
    int o1 = o0 + v.x, o2 = o1 + v.y, o3 = o2 + v.z;
    if (base + 3 < N) {
        int4 o = make_int4(o0, o1, o2, o3);
        *(int4*)(rowptr + base) = o;
        *(int4*)(cnt + base) = o;
    } else {
        if (base + 0 < N) { rowptr[base + 0] = o0; cnt[base + 0] = o0; }
        if (base + 1 < N) { rowptr[base + 1] = o1; cnt[base + 1] = o1; }
        if (base + 2 < N) { rowptr[base + 2] = o2; cnt[base + 2] = o2; }
    }
    if (b == 0 && tid == 255) rowptr[N] = bpre[255];
}

template<int F32>
__device__ void scatter_body(const int* __restrict__ ei, const void* __restrict__ attr,
                             int E, int N, int is64, int* __restrict__ cursor,
                             uint2* __restrict__ csr) {
    int e = blockIdx.x * blockDim.x + threadIdx.x;
    if (e >= E) return;
    int d = ld_idx(ei, (long long)E + e, is64, N);
    int s = ld_idx(ei, (long long)e, is64, N);
    float av = ldf<F32>(attr, e);
    int pos = atomicAdd(&cursor[d], 1);
    csr[pos] = make_uint2((unsigned)s, __float_as_uint(av));
}

__global__ void scatter_kernel(const int* __restrict__ ei, const void* __restrict__ attr,
                               int E, int N, const int* __restrict__ flags,
                               int* __restrict__ cursor, uint2* __restrict__ csr) {
    if (flags[1]) scatter_body<1>(ei, attr, E, N, flags[0], cursor, csr);
    else          scatter_body<0>(ei, attr, E, N, flags[0], cursor, csr);
}

// ================= Layer-1 aggregation =================
// r9 loop structure (4x batch); exp2-domain logits (constants premultiplied by LOG2E).

template<int F32, int P4>
__device__ void agg1_body(
    const int* __restrict__ rowptr, const void* __restrict__ csr,
    const void* __restrict__ x,
    const void* W1l, const void* b1l, const void* W1r, const void* b1r,
    const void* We1, const void* att1, const void* bias1, const void* g1v, const void* beta1,
    bf16* __restrict__ hout, int N) {
    int w0 = __builtin_amdgcn_readfirstlane((blockIdx.x * blockDim.x + threadIdx.x) >> 6);
    int NW = (gridDim.x * blockDim.x) >> 6;
    int lane = threadIdx.x & 63;
    int h = lane >> 4, q = lane & 15;
    int ja = h * 32 + q, jb = ja + 16;

    float wlaA = ldf<F32>(W1l, ja),      wlaB = ldf<F32>(W1l, jb);
    float wlbA = ldf<F32>(W1l, 128 + ja), wlbB = ldf<F32>(W1l, 128 + jb);
    float wraA = ldf<F32>(W1r, ja),      wraB = ldf<F32>(W1r, jb);
    float wrbA = ldf<F32>(W1r, 128 + ja), wrbB = ldf<F32>(W1r, 128 + jb);
    float blA = ldf<F32>(b1l, ja), blB = ldf<F32>(b1l, jb);
    float brA = ldf<F32>(b1r, ja), brB = ldf<F32>(b1r, jb);
    float weA = ldf<F32>(We1, ja), weB = ldf<F32>(We1, jb);
    float atA = ldf<F32>(att1, ja), atB = ldf<F32>(att1, jb);
    float aa4A = (0.4f * LOG2E) * atA, aa4B = (0.4f * LOG2E) * atB;
    float blbrA = blA + brA, blbrB = blB + brB;
    const float c6 = 0.6f * LOG2E;
    float P0 = c6 * red16(atA * wlaA + atB * wlaB);
    float P1 = c6 * red16(atA * wlbA + atB * wlbB);
    float Pw = c6 * red16(atA * weA + atB * weB);
    float Q0 = c6 * red16(atA * wraA + atB * wraB);
    float Q1 = c6 * red16(atA * wrbA + atB * wrbB);
    float Qc = c6 * red16(atA * blbrA + atB * blbrB);
    float biasA = ldf<F32>(bias1, q), biasB = ldf<F32>(bias1, q + 16);
    float gA = ldf<F32>(g1v, q), gB = ldf<F32>(g1v, q + 16);
    float beA = ldf<F32>(beta1, q), beB = ldf<F32>(beta1, q + 16);

    for (int n = w0; n < N; n += NW) {
        int beg = rowptr[n], end = rowptr[n + 1];
        float xd0, xd1;
        ldx<F32>(x, n, xd0, xd1);
        float cA = fmaf(xd0, wraA, fmaf(xd1, wrbA, blbrA));
        float cB = fmaf(xd0, wraB, fmaf(xd1, wrbB, blbrB));
        float Kn = fmaf(xd0, Q0, fmaf(xd1, Q1, Qc));
        float S = 0.f, Sx0 = 0.f, Sx1 = 0.f;

        auto edge = [&](float xs0, float xs1, float a) {
            float zA = fmaf(xs0, wlaA, fmaf(xs1, wlbA, fmaf(a, weA, cA)));
            float zB = fmaf(xs0, wlaB, fmaf(xs1, wlbB, fmaf(a, weB, cB)));
            float pabs = red16(fmaf(fabsf(zA), aa4A, fabsf(zB) * aa4B));
            float p = sclamp(fmaf(xs0, P0, fmaf(xs1, P1, fmaf(a, Pw, Kn))) + pabs, 86.f);
            float e = __builtin_exp2f(p);       // exp2-domain: single v_exp
            S += e;
            Sx0 = fmaf(e, xs0, Sx0);
            Sx1 = fmaf(e, xs1, Sx1);
        };

        int k = beg;
        for (; k + 4 <= end; k += 4) {          // 4x batch (r9 structure)
            int s0, s1, s2, s3;
            float a0, a1, a2, a3;
            ldrec<P4>(csr, k, s0, a0);
            ldrec<P4>(csr, k + 1, s1, a1);
            ldrec<P4>(csr, k + 2, s2, a2);
            ldrec<P4>(csr, k + 3, s3, a3);
            float p0, p1, q0, q1, r0, r1, t0, t1;
            ldx<F32>(x, s0, p0, p1);
            ldx<F32>(x, s1, q0, q1);
            ldx<F32>(x, s2, r0, r1);
            ldx<F32>(x, s3, t0, t1);
            edge(p0, p1, a0);
            edge(q0, q1, a1);
            edge(r0, r1, a2);
            edge(t0, t1, a3);
        }
        for (; k < end; ++k) {
            int s0; float a0;
            ldrec<P4>(csr, k, s0, a0);
            float p0, p1;
            ldx<F32>(x, s0, p0, p1);
            edge(p0, p1, a0);
        }

        float inv = 1.0f / (S + 1e-16f);
        float R = S * inv, U0 = Sx0 * inv, U1 = Sx1 * inv;
        float outA = fmaf(U0, wlaA, fmaf(U1, wlbA, R * blA));
        float outB = fmaf(U0, wlaB, fmaf(U1, wlbB, R * blB));
        outA += __shfl_xor(outA, 16); outA += __shfl_xor(outA, 32);
        outB += __shfl_xor(outB, 16); outB += __shfl_xor(outB, 32);
        float valA = fmaf(0.25f, outA, biasA);
        float valB = fmaf(0.25f, outB, biasB);
        float mu = red16(valA + valB) * (1.f / 32.f);
        float dA = valA - mu, dB = valB - mu;
        float var = red16(dA * dA + dB * dB) * (1.f / 32.f);
        float rs = rsqrtf(var + LN_EPS);
        float yA = fmaf(dA * rs, gA, beA);
        float yB = fmaf(dB * rs, gB, beB);
        float hA = yA > 0.f ? yA : expm1f(yA);
        float hB = yB > 0.f ? yB : expm1f(yB);
        if (lane < 16) {
            hout[n * 32 + q]      = f2b(hA);
            hout[n * 32 + 16 + q] = f2b(hB);
        }
    }
}

template<int P4>
__global__ __launch_bounds__(256) void agg1_kernel(
    const int* __restrict__ flags,
    const int* __restrict__ rowptr, const void* __restrict__ csr,
    const void* __restrict__ x,
    const void* W1l, const void* b1l, const void* W1r, const void* b1r,
    const void* We1, const void* att1, const void* bias1, const void* g1v, const void* beta1,
    bf16* __restrict__ hout, int N) {
    if (flags[1]) agg1_body<1, P4>(rowptr, csr, x, W1l, b1l, W1r, b1r,
                                   We1, att1, bias1, g1v, beta1, hout, N);
    else          agg1_body<0, P4>(rowptr, csr, x, W1l, b1l, W1r, b1r,
                                   We1, att1, bias1, g1v, beta1, hout, N);
}

// ================= Layer-2 node transform, in-place over hbuf =================

template<int F32>
__device__ void node2_body(bf16* __restrict__ hbuf, float* wl, float* wr,
                           const void* W2l, const void* b2l, const void* W2r, const void* b2r,
                           int N) {
    __shared__ float bl[16], br[16];
    int tid = threadIdx.x;
    for (int i = tid; i < 512; i += 256) { wl[i] = ldf<F32>(W2l, i); wr[i] = ldf<F32>(W2r, i); }
    if (tid < 16) { bl[tid] = ldf<F32>(b2l, tid); br[tid] = ldf<F32>(b2r, tid); }
    __syncthreads();
    int n = blockIdx.x * blockDim.x + tid;
    if (n >= N) return;
    float hv[32];
    #pragma unroll
    for (int c = 0; c < 32; ++c) hv[c] = b2f(hbuf[n * 32 + c]);
    float accl[16], accr[16];
    #pragma unroll
    for (int o = 0; o < 16; ++o) { accl[o] = bl[o]; accr[o] = br[o]; }
    #pragma unroll
    for (int c = 0; c < 32; ++c) {
        #pragma unroll
        for (int o = 0; o < 16; ++o) {
            accl[o] = fmaf(hv[c], wl[c * 16 + o], accl[o]);
            accr[o] = fmaf(hv[c], wr[c * 16 + o], accr[o]);
        }
    }
    #pragma unroll
    for (int o = 0; o < 16; ++o) {
        hbuf[n * 32 + o]      = f2b(accl[o]);   // h2l
        hbuf[n * 32 + 16 + o] = f2b(accr[o]);   // h2r
    }
}

__global__ __launch_bounds__(256) void node2_kernel(
    const int* __restrict__ flags, bf16* __restrict__ hbuf,
    const void* W2l, const void* b2l, const void* W2r, const void* b2r, int N) {
    __shared__ float wl[512], wr[512];
    if (flags[1]) node2_body<1>(hbuf, wl, wr, W2l, b2l, W2r, b2r, N);
    else          node2_body<0>(hbuf, wl, wr, W2l, b2l, W2r, b2r, N);
}

// ================= Layer-2 aggregation =================

template<int F32, int P4>
__device__ void agg2_body(
    const int* __restrict__ rowptr, const void* __restrict__ csr,
    const bf16* __restrict__ h2,
    const void* We2, const void* att2, const void* bias2, const void* g2v, const void* beta2,
    void* __restrict__ out, int N) {
    int w0 = __builtin_amdgcn_readfirstlane((blockIdx.x * blockDim.x + threadIdx.x) >> 6);
    int NW = (gridDim.x * blockDim.x) >> 6;
    int lane = threadIdx.x & 63;
    int g = lane >> 4, t = lane & 15;

    float we = ldf<F32>(We2, t), at = LOG2E * ldf<F32>(att2, t);   // exp2-domain
    float bia = ldf<F32>(bias2, t), gg = ldf<F32>(g2v, t), bb = ldf<F32>(beta2, t);

    for (int n = w0; n < N; n += NW) {
        int beg = rowptr[n], end = rowptr[n + 1];
        float xr = b2f(h2[n * 32 + 16 + t]);   // h2r

        float S = 0.f, A = 0.f;
        auto edge = [&](float v, float a) {
            float m = fmaf(a, we, v + xr);
            m = fmaxf(m, NEG_SLOPE * m);
            float p = sclamp(red16(m * at), 86.f);
            float e = __builtin_exp2f(p);
            S += e;
            A = fmaf(e, v, A);
        };
        int k = beg + g;
        for (; k + 4 < end; k += 8) {
            int s0, s1; float a0, a1;
            ldrec<P4>(csr, k, s0, a0);
            ldrec<P4>(csr, k + 4, s1, a1);
            float v0 = b2f(h2[s0 * 32 + t]);
            float v1 = b2f(h2[s1 * 32 + t]);
            edge(v0, a0);
            edge(v1, a1);
        }
        if (k < end) {
            int s0; float a0;
            ldrec<P4>(csr, k, s0, a0);
            edge(b2f(h2[s0 * 32 + t]), a0);
        }
        S += __shfl_xor(S, 16); S += __shfl_xor(S, 32);
        A += __shfl_xor(A, 16); A += __shfl_xor(A, 32);
        float val = A / (S + 1e-16f) + bia;

        float mu = red16(val) * (1.f / 16.f);
        float d = val - mu;
        float var = red16(d * d) * (1.f / 16.f);
        float y = fmaf(d * rsqrtf(var + LN_EPS), gg, bb);
        if (lane < 16) {
            if (F32) ((float*)out)[n * 16 + t] = y;
            else     ((bf16*)out)[n * 16 + t] = f2b(y);
        }
    }
}

template<int P4>
__global__ __launch_bounds__(256) void agg2_kernel(
    const int* __restrict__ flags,
    const int* __restrict__ rowptr, const void* __restrict__ csr,
    const bf16* __restrict__ h2,
    const void* We2, const void* att2, const void* bias2, const void* g2v, const void* beta2,
    void* __restrict__ out, int N) {
    if (flags[1]) agg2_body<1, P4>(rowptr, csr, h2, We2, att2, bias2, g2v, beta2, out, N);
    else          agg2_body<0, P4>(rowptr, csr, h2, We2, att2, bias2, g2v, beta2, out, N);
}

// ================= host =================

static inline size_t align256(size_t x) { return (x + 255) & ~size_t(255); }

extern "C" void kernel_launch(void* const* d_in, const int* in_sizes, int n_in,
                              void* d_out, int out_size, void* d_ws, size_t ws_size,
                              hipStream_t stream) {
    const void* x     = d_in[0];
    const int*  ei    = (const int*)d_in[1];
    const void* eattr = d_in[2];
    const void* W1l   = d_in[3];
    const void* b1l   = d_in[4];
    const void* W1r   = d_in[5];
    const void* b1r   = d_in[6];
    const void* We1   = d_in[7];
    const void* att1  = d_in[8];
    const void* bias1 = d_in[9];
    const void* g1    = d_in[10];
    const void* beta1 = d_in[11];
    const void* W2l   = d_in[12];
    const void* b2l   = d_in[13];
    const void* W2r   = d_in[14];
    const void* b2r   = d_in[15];
    const void* We2   = d_in[16];
    const void* att2  = d_in[17];
    const void* bias2 = d_in[18];
    const void* g2    = d_in[19];
    const void* beta2 = d_in[20];

    const int N = in_sizes[0] / 2;   // x is (N,2)
    const int E = in_sizes[2];       // edge_attr is (E,1)
    const bool p4 = (N <= 65536);
    const int EB = (E + ACHUNK - 1) / ACHUNK;

    char* ws = (char*)d_ws;
    size_t off = 0;
    int* flags   = (int*)(ws + off); off += align256(sizeof(int) * 2);
    int* bcnt    = (int*)(ws + off); off += align256(sizeof(int) * 1024);
    int* bbase   = (int*)(ws + off); off += align256(sizeof(int) * 257);
    int* bcursor = (int*)(ws + off); off += align256(sizeof(int) * 256);
    int* rowptr  = (int*)(ws + off); off += align256(sizeof(int) * (size_t)(N + 1));
    void* csr    = (void*)(ws + off); off += align256((p4 ? 4u : 8u) * (size_t)E);
    char* big    = (ws + off);
    uint2* binned = (uint2*)big;
    int*   cnt    = (int*)big;
    bf16*  hbuf   = (bf16*)big;

    if (p4) {
        hipMemsetAsync(bcnt, 0, sizeof(int) * 256, stream);
        histb_kernel<<<EB, 256, 0, stream>>>(ei, (const unsigned short*)x, E, N, flags, bcnt);
        scanb_kernel<<<1, 256, 0, stream>>>(bcnt, bbase, bcursor, rowptr, N, E);
        bina_kernel<<<EB, 256, 0, stream>>>(ei, eattr, E, N, flags, bcursor, binned);
        passb_kernel<<<(N + 255) >> 8, 256, 0, stream>>>(binned, bbase, rowptr, (unsigned*)csr, N);
    } else {
        cnt = (int*)big;
        hbuf = (bf16*)(big + align256(sizeof(int) * (size_t)N));
        const int B = (N + SCAN_TILE - 1) / SCAN_TILE;
        hipMemsetAsync(cnt, 0, sizeof(int) * (size_t)N, stream);
        hist_kernel<<<(E + 255) / 256, 256, 0, stream>>>(ei, (const unsigned short*)x, E, N, flags, cnt);
        scan_partial<<<B, 256, 0, stream>>>(cnt, bcnt, N);
        scan_final<<<B, 256, 0, stream>>>(cnt, rowptr, bcnt, N, B);
        scatter_kernel<<<(E + 255) / 256, 256, 0, stream>>>(ei, eattr, E, N, flags, cnt, (uint2*)csr);
    }

    if (p4) agg1_kernel<1><<<2048, 256, 0, stream>>>(flags, rowptr, csr, x,
                                                     W1l, b1l, W1r, b1r, We1, att1,
                                                     bias1, g1, beta1, hbuf, N);
    else    agg1_kernel<0><<<2048, 256, 0, stream>>>(flags, rowptr, csr, x,
                                                     W1l, b1l, W1r, b1r, We1, att1,
                                                     bias1, g1, beta1, hbuf, N);

    node2_kernel<<<(N + 255) / 256, 256, 0, stream>>>(flags, hbuf, W2l, b2l, W2r, b2r, N);

    if (p4) agg2_kernel<1><<<2048, 256, 0, stream>>>(flags, rowptr, csr, hbuf,
                                                     We2, att2, bias2, g2, beta2, d_out, N);
    else    agg2_kernel<0><<<2048, 256, 0, stream>>>(flags, rowptr, csr, hbuf,
                                                     We2, att2, bias2, g2, beta2, d_out, N);
}

// Round 12
// 226.858 us; speedup vs baseline: 1.0356x; 1.0038x over previous
//
#include <hip/hip_runtime.h>
#include <hip/hip_bf16.h>
#include <math.h>

typedef __hip_bfloat16 bf16;

__device__ __forceinline__ float b2f(bf16 v) { return __bfloat162float(v); }
__device__ __forceinline__ bf16  f2b(float v) { return __float2bfloat16(v); }

template<int F32>
__device__ __forceinline__ float ldf(const void* p, int i) {
    return F32 ? ((const float*)p)[i] : b2f(((const bf16*)p)[i]);
}
// load x[2s], x[2s+1] as one dword (bf16) or dwordx2 (f32)
template<int F32>
__device__ __forceinline__ void ldx(const void* x, int s, float& x0, float& x1) {
    if (F32) { float2 v = ((const float2*)x)[s]; x0 = v.x; x1 = v.y; }
    else {
        unsigned u = ((const unsigned*)x)[s];
        x0 = __uint_as_float((u & 0xFFFFu) << 16);
        x1 = __uint_as_float(u & 0xFFFF0000u);
    }
}
// f32 -> bf16 bits (RNE), returned in HIGH 16 bits
__device__ __forceinline__ unsigned f2b_hi(float f) {
    unsigned u = __float_as_uint(f);
    u += 0x7FFFu + ((u >> 16) & 1u);
    return u & 0xFFFF0000u;
}
// CSR record: P4 -> 4B (attr_hi16 | src16, needs N<=65536); else 8B (src, attr_f32bits)
template<int P4>
__device__ __forceinline__ void ldrec(const void* csr, int k, int& s, float& a) {
    if (P4) {
        unsigned u = ((const unsigned*)csr)[k];
        s = (int)(u & 0xFFFFu);
        a = __uint_as_float(u & 0xFFFF0000u);
    } else {
        uint2 r = ((const uint2*)csr)[k];
        s = (int)r.x;
        a = __uint_as_float(r.y);
    }
}
__device__ __forceinline__ float sclamp(float v, float lim) {
    return fminf(fmaxf(v, -lim), lim);
}
// VALU-only sum over each 16-lane row
template<int CTRL>
__device__ __forceinline__ float dpp_add(float v) {
    int t = __builtin_amdgcn_update_dpp(0, __float_as_int(v), CTRL, 0xF, 0xF, true);
    return v + __int_as_float(t);
}
__device__ __forceinline__ float red16(float v) {
    v = dpp_add<0xB1>(v);    // quad_perm [1,0,3,2]
    v = dpp_add<0x4E>(v);    // quad_perm [2,3,0,1]
    v = dpp_add<0x124>(v);   // row_ror:4
    v = dpp_add<0x128>(v);   // row_ror:8
    return v;
}

#define NEG_SLOPE 0.2f
#define LN_EPS 1e-5f
#define SCAN_TILE 1024
#define ACHUNK 2048     // edges per bucket-bin block (halved: 2 blocks/CU co-resident)

__device__ __forceinline__ int ld_idx(const int* ei, long long pos, int is64, int N) {
    int v = is64 ? ei[2 * pos] : ei[pos];
    return min(max(v, 0), N - 1);
}
__device__ __forceinline__ int calc_is64(const int* ei) {
    int hi = 0, nz = 0;
    #pragma unroll
    for (int i = 0; i < 8; ++i) { hi |= ei[2 * i + 1]; nz |= ei[2 * i]; }
    return (hi == 0 && nz != 0) ? 1 : 0;
}

// ================= bucketed CSR build (N <= 65536): all scatter in LDS =================

__global__ __launch_bounds__(256) void histb_kernel(const int* __restrict__ ei,
                                                    const unsigned short* __restrict__ xu,
                                                    int E, int N, int* __restrict__ flags,
                                                    int* __restrict__ bcnt) {
    __shared__ int c[256];
    int tid = threadIdx.x;
    c[tid] = 0;
    int is64 = calc_is64(ei);
    if (blockIdx.x == 0 && tid == 0) {
        flags[0] = is64;
        int pl = 0;
        for (int i = 0; i < 32; ++i) {
            unsigned ex = (xu[2 * i] >> 7) & 0xFF;
            if (ex >= 100 && ex <= 140) pl++;
        }
        flags[1] = (pl >= 24) ? 0 : 1;   // 1 = float tensors are fp32
    }
    __syncthreads();
    int i0 = blockIdx.x * ACHUNK;
    int iend = min(i0 + ACHUNK, E);
    for (int i = i0 + tid; i < iend; i += 256)
        atomicAdd(&c[ld_idx(ei, (long long)E + i, is64, N) >> 8], 1);
    __syncthreads();
    if (c[tid]) atomicAdd(&bcnt[tid], c[tid]);
}

__global__ void scanb_kernel(const int* __restrict__ bcnt, int* __restrict__ bbase,
                             int* __restrict__ bcursor, int* __restrict__ rowptr,
                             int N, int E) {
    __shared__ int s[256];
    int tid = threadIdx.x;
    int v = bcnt[tid];
    s[tid] = v;
    __syncthreads();
    for (int off = 1; off < 256; off <<= 1) {
        int u = (tid >= off) ? s[tid - off] : 0;
        __syncthreads();
        s[tid] += u;
        __syncthreads();
    }
    int excl = s[tid] - v;
    bbase[tid] = excl;
    bcursor[tid] = excl;
    if (tid == 255) { bbase[256] = s[255]; rowptr[N] = E; }
}

template<int F32>
__device__ void bina_body(const int* __restrict__ ei, const void* __restrict__ attr,
                          int E, int N, int is64, int* __restrict__ bcursor,
                          uint2* __restrict__ binned) {
    __shared__ int cnt[256], incl[256], cur[256];
    __shared__ uint2 stage[ACHUNK];   // 16 KB
    int tid = threadIdx.x;
    cnt[tid] = 0;
    __syncthreads();
    int i0 = blockIdx.x * ACHUNK;
    int iend = min(i0 + ACHUNK, E);
    for (int i = i0 + tid; i < iend; i += 256)
        atomicAdd(&cnt[ld_idx(ei, (long long)E + i, is64, N) >> 8], 1);
    __syncthreads();
    incl[tid] = cnt[tid];
    __syncthreads();
    for (int off = 1; off < 256; off <<= 1) {
        int u = (tid >= off) ? incl[tid - off] : 0;
        __syncthreads();
        incl[tid] += u;
        __syncthreads();
    }
    cur[tid] = incl[tid] - cnt[tid];
    __syncthreads();
    for (int i = i0 + tid; i < iend; i += 256) {
        int d = ld_idx(ei, (long long)E + i, is64, N);
        int s = ld_idx(ei, (long long)i, is64, N);
        float a = ldf<F32>(attr, i);
        int p = atomicAdd(&cur[d >> 8], 1);
        stage[p] = make_uint2((unsigned)s | ((unsigned)(d & 255) << 16), f2b_hi(a));
    }
    __syncthreads();
    int c = cnt[tid];
    if (c > 0) {
        int start = incl[tid] - c;
        int g = atomicAdd(&bcursor[tid], c);
        for (int j = 0; j < c; ++j) binned[g + j] = stage[start + j];
    }
}

__global__ __launch_bounds__(256) void bina_kernel(const int* __restrict__ ei,
                                                   const void* __restrict__ attr,
                                                   int E, int N, const int* __restrict__ flags,
                                                   int* __restrict__ bcursor,
                                                   uint2* __restrict__ binned) {
    if (flags[1]) bina_body<1>(ei, attr, E, N, flags[0], bcursor, binned);
    else          bina_body<0>(ei, attr, E, N, flags[0], bcursor, binned);
}

__global__ __launch_bounds__(256) void passb_kernel(const uint2* __restrict__ binned,
                                                    const int* __restrict__ bbase,
                                                    int* __restrict__ rowptr,
                                                    unsigned* __restrict__ csr, int N) {
    __shared__ int nc[256], incl[256], cur[256];
    int b = blockIdx.x, tid = threadIdx.x;
    int base = bbase[b], cntb = bbase[b + 1] - base;
    nc[tid] = 0;
    __syncthreads();
    for (int i = tid; i < cntb; i += 256)
        atomicAdd(&nc[(binned[base + i].x >> 16) & 255], 1);
    __syncthreads();
    incl[tid] = nc[tid];
    __syncthreads();
    for (int off = 1; off < 256; off <<= 1) {
        int u = (tid >= off) ? incl[tid - off] : 0;
        __syncthreads();
        incl[tid] += u;
        __syncthreads();
    }
    int excl = incl[tid] - nc[tid];
    int node = (b << 8) + tid;
    if (node < N) rowptr[node] = base + excl;
    cur[tid] = excl;
    __syncthreads();
    for (int i = tid; i < cntb; i += 256) {
        uint2 r = binned[base + i];
        int p = atomicAdd(&cur[(r.x >> 16) & 255], 1);
        csr[base + p] = r.y | (r.x & 0xFFFFu);
    }
}

// ================= fallback CSR build (N > 65536) =================

__global__ void hist_kernel(const int* __restrict__ ei, const unsigned short* __restrict__ xu,
                            int E, int N, int* __restrict__ flags, int* __restrict__ cnt) {
    int is64 = calc_is64(ei);
    if (blockIdx.x == 0 && threadIdx.x == 0) {
        flags[0] = is64;
        int pl = 0;
        for (int i = 0; i < 32; ++i) {
            unsigned ex = (xu[2 * i] >> 7) & 0xFF;
            if (ex >= 100 && ex <= 140) pl++;
        }
        flags[1] = (pl >= 24) ? 0 : 1;
    }
    int e = blockIdx.x * blockDim.x + threadIdx.x;
    if (e >= E) return;
    atomicAdd(&cnt[ld_idx(ei, (long long)E + e, is64, N)], 1);
}

__global__ __launch_bounds__(256) void scan_partial(const int* __restrict__ cnt,
                                                    int* __restrict__ bsum, int N) {
    __shared__ int wsum[4];
    int b = blockIdx.x, tid = threadIdx.x;
    int base = b * SCAN_TILE + tid * 4;
    int4 v = make_int4(0, 0, 0, 0);
    if (base + 3 < N) v = *(const int4*)(cnt + base);
    else {
        if (base + 0 < N) v.x = cnt[base + 0];
        if (base + 1 < N) v.y = cnt[base + 1];
        if (base + 2 < N) v.z = cnt[base + 2];
    }
    int s = v.x + v.y + v.z + v.w;
    #pragma unroll
    for (int off = 1; off < 64; off <<= 1) s += __shfl_xor(s, off);
    if ((tid & 63) == 0) wsum[tid >> 6] = s;
    __syncthreads();
    if (tid == 0) bsum[b] = wsum[0] + wsum[1] + wsum[2] + wsum[3];
}

__global__ __launch_bounds__(256) void scan_final(int* __restrict__ cnt, int* __restrict__ rowptr,
                                                  const int* __restrict__ bsum, int N, int B) {
    __shared__ int tsum[256];
    __shared__ int bpre[256];
    int b = blockIdx.x, tid = threadIdx.x;
    bpre[tid] = (tid < B) ? bsum[tid] : 0;
    int base = b * SCAN_TILE + tid * 4;
    int4 v = make_int4(0, 0, 0, 0);
    if (base + 3 < N) v = *(const int4*)(cnt + base);
    else {
        if (base + 0 < N) v.x = cnt[base + 0];
        if (base + 1 < N) v.y = cnt[base + 1];
        if (base + 2 < N) v.z = cnt[base + 2];
    }
    tsum[tid] = v.x + v.y + v.z + v.w;
    __syncthreads();
    for (int off = 1; off < 256; off <<= 1) {
        int t = (tid >= off) ? tsum[tid - off] : 0;
        int u = (tid >= off) ? bpre[tid - off] : 0;
        __syncthreads();
        tsum[tid] += t;
        bpre[tid] += u;
        __syncthreads();
    }
    int blockpre = (b == 0) ? 0 : bpre[b - 1];
    int o0 = blockpre + ((tid == 0) ? 0 : tsum[tid - 1]);
    int o1 = o0 + v.x, o2 = o1 + v.y, o3 = o2 + v.z;
    if (base + 3 < N) {
        int4 o = make_int4(o0, o1, o2, o3);
        *(int4*)(rowptr + base) = o;
        *(int4*)(cnt + base) = o;
    } else {
        if (base + 0 < N) { rowptr[base + 0] = o0; cnt[base + 0] = o0; }
        if (base + 1 < N) { rowptr[base + 1] = o1; cnt[base + 1] = o1; }
        if (base + 2 < N) { rowptr[base + 2] = o2; cnt[base + 2] = o2; }
    }
    if (b == 0 && tid == 255) rowptr[N] = bpre[255];
}

template<int F32>
__device__ void scatter_body(const int* __restrict__ ei, const void* __restrict__ attr,
                             int E, int N, int is64, int* __restrict__ cursor,
                             uint2* __restrict__ csr) {
    int e = blockIdx.x * blockDim.x + threadIdx.x;
    if (e >= E) return;
    int d = ld_idx(ei, (long long)E + e, is64, N);
    int s = ld_idx(ei, (long long)e, is64, N);
    float av = ldf<F32>(attr, e);
    int pos = atomicAdd(&cursor[d], 1);
    csr[pos] = make_uint2((unsigned)s, __float_as_uint(av));
}

__global__ void scatter_kernel(const int* __restrict__ ei, const void* __restrict__ attr,
                               int E, int N, const int* __restrict__ flags,
                               int* __restrict__ cursor, uint2* __restrict__ csr) {
    if (flags[1]) scatter_body<1>(ei, attr, E, N, flags[0], cursor, csr);
    else          scatter_body<0>(ei, attr, E, N, flags[0], cursor, csr);
}

// ================= Layer-1 aggregation (r9 structure — best measured) =================

template<int F32, int P4>
__device__ void agg1_body(
    const int* __restrict__ rowptr, const void* __restrict__ csr,
    const void* __restrict__ x,
    const void* W1l, const void* b1l, const void* W1r, const void* b1r,
    const void* We1, const void* att1, const void* bias1, const void* g1v, const void* beta1,
    bf16* __restrict__ hout, int N) {
    int w0 = __builtin_amdgcn_readfirstlane((blockIdx.x * blockDim.x + threadIdx.x) >> 6);
    int NW = (gridDim.x * blockDim.x) >> 6;
    int lane = threadIdx.x & 63;
    int h = lane >> 4, q = lane & 15;
    int ja = h * 32 + q, jb = ja + 16;

    float wlaA = ldf<F32>(W1l, ja),      wlaB = ldf<F32>(W1l, jb);
    float wlbA = ldf<F32>(W1l, 128 + ja), wlbB = ldf<F32>(W1l, 128 + jb);
    float wraA = ldf<F32>(W1r, ja),      wraB = ldf<F32>(W1r, jb);
    float wrbA = ldf<F32>(W1r, 128 + ja), wrbB = ldf<F32>(W1r, 128 + jb);
    float blA = ldf<F32>(b1l, ja), blB = ldf<F32>(b1l, jb);
    float brA = ldf<F32>(b1r, ja), brB = ldf<F32>(b1r, jb);
    float weA = ldf<F32>(We1, ja), weB = ldf<F32>(We1, jb);
    float atA = ldf<F32>(att1, ja), atB = ldf<F32>(att1, jb);
    float aa4A = 0.4f * atA, aa4B = 0.4f * atB;
    float blbrA = blA + brA, blbrB = blB + brB;
    float P0 = 0.6f * red16(atA * wlaA + atB * wlaB);
    float P1 = 0.6f * red16(atA * wlbA + atB * wlbB);
    float Pw = 0.6f * red16(atA * weA + atB * weB);
    float Q0 = 0.6f * red16(atA * wraA + atB * wraB);
    float Q1 = 0.6f * red16(atA * wrbA + atB * wrbB);
    float Qc = 0.6f * red16(atA * blbrA + atB * blbrB);
    float biasA = ldf<F32>(bias1, q), biasB = ldf<F32>(bias1, q + 16);
    float gA = ldf<F32>(g1v, q), gB = ldf<F32>(g1v, q + 16);
    float beA = ldf<F32>(beta1, q), beB = ldf<F32>(beta1, q + 16);

    for (int n = w0; n < N; n += NW) {
        int beg = rowptr[n], end = rowptr[n + 1];
        float xd0, xd1;
        ldx<F32>(x, n, xd0, xd1);
        float cA = fmaf(xd0, wraA, fmaf(xd1, wrbA, blbrA));
        float cB = fmaf(xd0, wraB, fmaf(xd1, wrbB, blbrB));
        float Kn = fmaf(xd0, Q0, fmaf(xd1, Q1, Qc));
        float S = 0.f, Sx0 = 0.f, Sx1 = 0.f;

        auto edge = [&](float xs0, float xs1, float a) {
            float zA = fmaf(xs0, wlaA, fmaf(xs1, wlbA, fmaf(a, weA, cA)));
            float zB = fmaf(xs0, wlaB, fmaf(xs1, wlbB, fmaf(a, weB, cB)));
            float pabs = red16(fmaf(fabsf(zA), aa4A, fabsf(zB) * aa4B));
            float p = sclamp(fmaf(xs0, P0, fmaf(xs1, P1, fmaf(a, Pw, Kn))) + pabs, 60.f);
            float e = __expf(p);
            S += e;
            Sx0 = fmaf(e, xs0, Sx0);
            Sx1 = fmaf(e, xs1, Sx1);
        };

        int k = beg;
        for (; k + 4 <= end; k += 4) {          // 4x batch
            int s0, s1, s2, s3;
            float a0, a1, a2, a3;
            ldrec<P4>(csr, k, s0, a0);
            ldrec<P4>(csr, k + 1, s1, a1);
            ldrec<P4>(csr, k + 2, s2, a2);
            ldrec<P4>(csr, k + 3, s3, a3);
            float p0, p1, q0, q1, r0, r1, t0, t1;
            ldx<F32>(x, s0, p0, p1);
            ldx<F32>(x, s1, q0, q1);
            ldx<F32>(x, s2, r0, r1);
            ldx<F32>(x, s3, t0, t1);
            edge(p0, p1, a0);
            edge(q0, q1, a1);
            edge(r0, r1, a2);
            edge(t0, t1, a3);
        }
        for (; k < end; ++k) {
            int s0; float a0;
            ldrec<P4>(csr, k, s0, a0);
            float p0, p1;
            ldx<F32>(x, s0, p0, p1);
            edge(p0, p1, a0);
        }

        float inv = 1.0f / (S + 1e-16f);
        float R = S * inv, U0 = Sx0 * inv, U1 = Sx1 * inv;
        float outA = fmaf(U0, wlaA, fmaf(U1, wlbA, R * blA));
        float outB = fmaf(U0, wlaB, fmaf(U1, wlbB, R * blB));
        outA += __shfl_xor(outA, 16); outA += __shfl_xor(outA, 32);
        outB += __shfl_xor(outB, 16); outB += __shfl_xor(outB, 32);
        float valA = fmaf(0.25f, outA, biasA);
        float valB = fmaf(0.25f, outB, biasB);
        float mu = red16(valA + valB) * (1.f / 32.f);
        float dA = valA - mu, dB = valB - mu;
        float var = red16(dA * dA + dB * dB) * (1.f / 32.f);
        float rs = rsqrtf(var + LN_EPS);
        float yA = fmaf(dA * rs, gA, beA);
        float yB = fmaf(dB * rs, gB, beB);
        float hA = yA > 0.f ? yA : expm1f(yA);
        float hB = yB > 0.f ? yB : expm1f(yB);
        if (lane < 16) {
            hout[n * 32 + q]      = f2b(hA);
            hout[n * 32 + 16 + q] = f2b(hB);
        }
    }
}

template<int P4>
__global__ __launch_bounds__(256) void agg1_kernel(
    const int* __restrict__ flags,
    const int* __restrict__ rowptr, const void* __restrict__ csr,
    const void* __restrict__ x,
    const void* W1l, const void* b1l, const void* W1r, const void* b1r,
    const void* We1, const void* att1, const void* bias1, const void* g1v, const void* beta1,
    bf16* __restrict__ hout, int N) {
    if (flags[1]) agg1_body<1, P4>(rowptr, csr, x, W1l, b1l, W1r, b1r,
                                   We1, att1, bias1, g1v, beta1, hout, N);
    else          agg1_body<0, P4>(rowptr, csr, x, W1l, b1l, W1r, b1r,
                                   We1, att1, bias1, g1v, beta1, hout, N);
}

// ================= Layer-2 node transform, in-place over hbuf =================

template<int F32>
__device__ void node2_body(bf16* __restrict__ hbuf, float* wl, float* wr,
                           const void* W2l, const void* b2l, const void* W2r, const void* b2r,
                           int N) {
    __shared__ float bl[16], br[16];
    int tid = threadIdx.x;
    for (int i = tid; i < 512; i += 256) { wl[i] = ldf<F32>(W2l, i); wr[i] = ldf<F32>(W2r, i); }
    if (tid < 16) { bl[tid] = ldf<F32>(b2l, tid); br[tid] = ldf<F32>(b2r, tid); }
    __syncthreads();
    int n = blockIdx.x * blockDim.x + tid;
    if (n >= N) return;
    float hv[32];
    #pragma unroll
    for (int c = 0; c < 32; ++c) hv[c] = b2f(hbuf[n * 32 + c]);
    float accl[16], accr[16];
    #pragma unroll
    for (int o = 0; o < 16; ++o) { accl[o] = bl[o]; accr[o] = br[o]; }
    #pragma unroll
    for (int c = 0; c < 32; ++c) {
        #pragma unroll
        for (int o = 0; o < 16; ++o) {
            accl[o] = fmaf(hv[c], wl[c * 16 + o], accl[o]);
            accr[o] = fmaf(hv[c], wr[c * 16 + o], accr[o]);
        }
    }
    #pragma unroll
    for (int o = 0; o < 16; ++o) {
        hbuf[n * 32 + o]      = f2b(accl[o]);   // h2l
        hbuf[n * 32 + 16 + o] = f2b(accr[o]);   // h2r
    }
}

__global__ __launch_bounds__(256) void node2_kernel(
    const int* __restrict__ flags, bf16* __restrict__ hbuf,
    const void* W2l, const void* b2l, const void* W2r, const void* b2r, int N) {
    __shared__ float wl[512], wr[512];
    if (flags[1]) node2_body<1>(hbuf, wl, wr, W2l, b2l, W2r, b2r, N);
    else          node2_body<0>(hbuf, wl, wr, W2l, b2l, W2r, b2r, N);
}

// ================= Layer-2 aggregation (r9 structure) =================

template<int F32, int P4>
__device__ void agg2_body(
    const int* __restrict__ rowptr, const void* __restrict__ csr,
    const bf16* __restrict__ h2,
    const void* We2, const void* att2, const void* bias2, const void* g2v, const void* beta2,
    void* __restrict__ out, int N) {
    int w0 = __builtin_amdgcn_readfirstlane((blockIdx.x * blockDim.x + threadIdx.x) >> 6);
    int NW = (gridDim.x * blockDim.x) >> 6;
    int lane = threadIdx.x & 63;
    int g = lane >> 4, t = lane & 15;

    float we = ldf<F32>(We2, t), at = ldf<F32>(att2, t);
    float bia = ldf<F32>(bias2, t), gg = ldf<F32>(g2v, t), bb = ldf<F32>(beta2, t);

    for (int n = w0; n < N; n += NW) {
        int beg = rowptr[n], end = rowptr[n + 1];
        float xr = b2f(h2[n * 32 + 16 + t]);   // h2r

        float S = 0.f, A = 0.f;
        auto edge = [&](float v, float a) {
            float m = fmaf(a, we, v + xr);
            m = fmaxf(m, NEG_SLOPE * m);
            float p = sclamp(red16(m * at), 60.f);
            float e = __expf(p);
            S += e;
            A = fmaf(e, v, A);
        };
        int k = beg + g;
        for (; k + 4 < end; k += 8) {
            int s0, s1; float a0, a1;
            ldrec<P4>(csr, k, s0, a0);
            ldrec<P4>(csr, k + 4, s1, a1);
            float v0 = b2f(h2[s0 * 32 + t]);
            float v1 = b2f(h2[s1 * 32 + t]);
            edge(v0, a0);
            edge(v1, a1);
        }
        if (k < end) {
            int s0; float a0;
            ldrec<P4>(csr, k, s0, a0);
            edge(b2f(h2[s0 * 32 + t]), a0);
        }
        S += __shfl_xor(S, 16); S += __shfl_xor(S, 32);
        A += __shfl_xor(A, 16); A += __shfl_xor(A, 32);
        float val = A / (S + 1e-16f) + bia;

        float mu = red16(val) * (1.f / 16.f);
        float d = val - mu;
        float var = red16(d * d) * (1.f / 16.f);
        float y = fmaf(d * rsqrtf(var + LN_EPS), gg, bb);
        if (lane < 16) {
            if (F32) ((float*)out)[n * 16 + t] = y;
            else     ((bf16*)out)[n * 16 + t] = f2b(y);
        }
    }
}

template<int P4>
__global__ __launch_bounds__(256) void agg2_kernel(
    const int* __restrict__ flags,
    const int* __restrict__ rowptr, const void* __restrict__ csr,
    const bf16* __restrict__ h2,
    const void* We2, const void* att2, const void* bias2, const void* g2v, const void* beta2,
    void* __restrict__ out, int N) {
    if (flags[1]) agg2_body<1, P4>(rowptr, csr, h2, We2, att2, bias2, g2v, beta2, out, N);
    else          agg2_body<0, P4>(rowptr, csr, h2, We2, att2, bias2, g2v, beta2, out, N);
}

// ================= host =================

static inline size_t align256(size_t x) { return (x + 255) & ~size_t(255); }

extern "C" void kernel_launch(void* const* d_in, const int* in_sizes, int n_in,
                              void* d_out, int out_size, void* d_ws, size_t ws_size,
                              hipStream_t stream) {
    const void* x     = d_in[0];
    const int*  ei    = (const int*)d_in[1];
    const void* eattr = d_in[2];
    const void* W1l   = d_in[3];
    const void* b1l   = d_in[4];
    const void* W1r   = d_in[5];
    const void* b1r   = d_in[6];
    const void* We1   = d_in[7];
    const void* att1  = d_in[8];
    const void* bias1 = d_in[9];
    const void* g1    = d_in[10];
    const void* beta1 = d_in[11];
    const void* W2l   = d_in[12];
    const void* b2l   = d_in[13];
    const void* W2r   = d_in[14];
    const void* b2r   = d_in[15];
    const void* We2   = d_in[16];
    const void* att2  = d_in[17];
    const void* bias2 = d_in[18];
    const void* g2    = d_in[19];
    const void* beta2 = d_in[20];

    const int N = in_sizes[0] / 2;   // x is (N,2)
    const int E = in_sizes[2];       // edge_attr is (E,1)
    const bool p4 = (N <= 65536);
    const int EB = (E + ACHUNK - 1) / ACHUNK;

    char* ws = (char*)d_ws;
    size_t off = 0;
    int* flags   = (int*)(ws + off); off += align256(sizeof(int) * 2);
    int* bcnt    = (int*)(ws + off); off += align256(sizeof(int) * 1024);
    int* bbase   = (int*)(ws + off); off += align256(sizeof(int) * 257);
    int* bcursor = (int*)(ws + off); off += align256(sizeof(int) * 256);
    int* rowptr  = (int*)(ws + off); off += align256(sizeof(int) * (size_t)(N + 1));
    void* csr    = (void*)(ws + off); off += align256((p4 ? 4u : 8u) * (size_t)E);
    char* big    = (ws + off);
    uint2* binned = (uint2*)big;
    int*   cnt    = (int*)big;
    bf16*  hbuf   = (bf16*)big;

    if (p4) {
        hipMemsetAsync(bcnt, 0, sizeof(int) * 256, stream);
        histb_kernel<<<EB, 256, 0, stream>>>(ei, (const unsigned short*)x, E, N, flags, bcnt);
        scanb_kernel<<<1, 256, 0, stream>>>(bcnt, bbase, bcursor, rowptr, N, E);
        bina_kernel<<<EB, 256, 0, stream>>>(ei, eattr, E, N, flags, bcursor, binned);
        passb_kernel<<<(N + 255) >> 8, 256, 0, stream>>>(binned, bbase, rowptr, (unsigned*)csr, N);
    } else {
        cnt = (int*)big;
        hbuf = (bf16*)(big + align256(sizeof(int) * (size_t)N));
        const int B = (N + SCAN_TILE - 1) / SCAN_TILE;
        hipMemsetAsync(cnt, 0, sizeof(int) * (size_t)N, stream);
        hist_kernel<<<(E + 255) / 256, 256, 0, stream>>>(ei, (const unsigned short*)x, E, N, flags, cnt);
        scan_partial<<<B, 256, 0, stream>>>(cnt, bcnt, N);
        scan_final<<<B, 256, 0, stream>>>(cnt, rowptr, bcnt, N, B);
        scatter_kernel<<<(E + 255) / 256, 256, 0, stream>>>(ei, eattr, E, N, flags, cnt, (uint2*)csr);
    }

    if (p4) agg1_kernel<1><<<2048, 256, 0, stream>>>(flags, rowptr, csr, x,
                                                     W1l, b1l, W1r, b1r, We1, att1,
                                                     bias1, g1, beta1, hbuf, N);
    else    agg1_kernel<0><<<2048, 256, 0, stream>>>(flags, rowptr, csr, x,
                                                     W1l, b1l, W1r, b1r, We1, att1,
                                                     bias1, g1, beta1, hbuf, N);

    node2_kernel<<<(N + 255) / 256, 256, 0, stream>>>(flags, hbuf, W2l, b2l, W2r, b2r, N);

    if (p4) agg2_kernel<1><<<2048, 256, 0, stream>>>(flags, rowptr, csr, hbuf,
                                                     We2, att2, bias2, g2, beta2, d_out, N);
    else    agg2_kernel<0><<<2048, 256, 0, stream>>>(flags, rowptr, csr, hbuf,
                                                     We2, att2, bias2, g2, beta2, d_out, N);
}

// Round 13
// 219.011 us; speedup vs baseline: 1.0727x; 1.0358x over previous
//
#include <hip/hip_runtime.h>
#include <hip/hip_bf16.h>
#include <math.h>

typedef __hip_bfloat16 bf16;

__device__ __forceinline__ float b2f(bf16 v) { return __bfloat162float(v); }
__device__ __forceinline__ bf16  f2b(float v) { return __float2bfloat16(v); }

template<int F32>
__device__ __forceinline__ float ldf(const void* p, int i) {
    return F32 ? ((const float*)p)[i] : b2f(((const bf16*)p)[i]);
}
template<int F32>
__device__ __forceinline__ void ldx(const void* x, int s, float& x0, float& x1) {
    if (F32) { float2 v = ((const float2*)x)[s]; x0 = v.x; x1 = v.y; }
    else {
        unsigned u = ((const unsigned*)x)[s];
        x0 = __uint_as_float((u & 0xFFFFu) << 16);
        x1 = __uint_as_float(u & 0xFFFF0000u);
    }
}
__device__ __forceinline__ unsigned f2b_hi(float f) {
    unsigned u = __float_as_uint(f);
    u += 0x7FFFu + ((u >> 16) & 1u);
    return u & 0xFFFF0000u;
}
template<int P4>
__device__ __forceinline__ void ldrec(const void* csr, int k, int& s, float& a) {
    if (P4) {
        unsigned u = ((const unsigned*)csr)[k];
        s = (int)(u & 0xFFFFu);
        a = __uint_as_float(u & 0xFFFF0000u);
    } else {
        uint2 r = ((const uint2*)csr)[k];
        s = (int)r.x;
        a = __uint_as_float(r.y);
    }
}
__device__ __forceinline__ float sclamp(float v, float lim) {
    return fminf(fmaxf(v, -lim), lim);
}
template<int CTRL>
__device__ __forceinline__ float dpp_add(float v) {
    int t = __builtin_amdgcn_update_dpp(0, __float_as_int(v), CTRL, 0xF, 0xF, true);
    return v + __int_as_float(t);
}
__device__ __forceinline__ float red16(float v) {
    v = dpp_add<0xB1>(v);
    v = dpp_add<0x4E>(v);
    v = dpp_add<0x124>(v);
    v = dpp_add<0x128>(v);
    return v;
}

#define NEG_SLOPE 0.2f
#define LN_EPS 1e-5f
#define SCAN_TILE 1024
#define ACHUNK 2048     // edges per build block (8 per thread)
#define EBMAX 512       // max build blocks supported by passb's LDS directory

__device__ __forceinline__ int ld_idx(const int* ei, long long pos, int is64, int N) {
    int v = is64 ? ei[2 * pos] : ei[pos];
    return min(max(v, 0), N - 1);
}
__device__ __forceinline__ int calc_is64(const int* ei) {
    int hi = 0, nz = 0;
    #pragma unroll
    for (int i = 0; i < 8; ++i) { hi |= ei[2 * i + 1]; nz |= ei[2 * i]; }
    return (hi == 0 && nz != 0) ? 1 : 0;
}
__device__ __forceinline__ int calc_isf32(const unsigned short* xu) {
    int pl = 0;
    for (int i = 0; i < 32; ++i) {
        unsigned ex = (xu[2 * i] >> 7) & 0xFF;
        if (ex >= 100 && ex <= 140) pl++;
    }
    return (pl >= 24) ? 0 : 1;
}

// ====== one-pass bucketed build (N<=65536, EB<=512): edges read exactly once ======
// Block b: bins its 2048 edges by bucket (dst>>8) in LDS, writes them bucket-grouped
// to its OWN region binned[b*ACHUNK..] (dense coalesced), plus directory
// cntm[b*256+bucket], locm[b*256+bucket] (run length / run start within region).

template<int F32>
__device__ void bina1_body(const int* __restrict__ ei, const void* __restrict__ attr,
                           int E, int N, int is64,
                           uint2* __restrict__ binned, int* __restrict__ cntm,
                           int* __restrict__ locm,
                           int* cnt, int* incl, int* cur, uint2* stage) {
    int tid = threadIdx.x, b = blockIdx.x;
    cnt[tid] = 0;
    __syncthreads();
    int i0 = b * ACHUNK;
    int iend = min(i0 + ACHUNK, E);
    uint2 rec[8]; int bk[8];
    #pragma unroll
    for (int r = 0; r < 8; ++r) {
        int i = i0 + tid + r * 256;
        bk[r] = -1;
        if (i < iend) {
            int d = ld_idx(ei, (long long)E + i, is64, N);
            int s = ld_idx(ei, (long long)i, is64, N);
            float a = ldf<F32>(attr, i);
            rec[r] = make_uint2((unsigned)s | ((unsigned)(d & 255) << 16), f2b_hi(a));
            bk[r] = d >> 8;
            atomicAdd(&cnt[bk[r]], 1);
        }
    }
    __syncthreads();
    incl[tid] = cnt[tid];
    __syncthreads();
    for (int off = 1; off < 256; off <<= 1) {
        int u = (tid >= off) ? incl[tid - off] : 0;
        __syncthreads();
        incl[tid] += u;
        __syncthreads();
    }
    cur[tid] = incl[tid] - cnt[tid];
    __syncthreads();
    #pragma unroll
    for (int r = 0; r < 8; ++r) {
        if (bk[r] >= 0) {
            int p = atomicAdd(&cur[bk[r]], 1);
            stage[p] = rec[r];
        }
    }
    __syncthreads();
    int n = iend - i0;
    for (int i = tid; i < n; i += 256)                 // dense coalesced region write
        binned[(size_t)b * ACHUNK + i] = stage[i];
    cntm[b * 256 + tid] = cnt[tid];                    // coalesced directory write
    locm[b * 256 + tid] = incl[tid] - cnt[tid];
}

__global__ __launch_bounds__(256) void bina1_kernel(const int* __restrict__ ei,
                                                    const void* __restrict__ attr,
                                                    const unsigned short* __restrict__ xu,
                                                    int E, int N, int* __restrict__ flags,
                                                    uint2* __restrict__ binned,
                                                    int* __restrict__ cntm,
                                                    int* __restrict__ locm) {
    __shared__ int cnt[256], incl[256], cur[256];
    __shared__ uint2 stage[ACHUNK];
    __shared__ int sflags[2];
    if (threadIdx.x == 0) {
        sflags[0] = calc_is64(ei);
        sflags[1] = calc_isf32(xu);
        if (blockIdx.x == 0) { flags[0] = sflags[0]; flags[1] = sflags[1]; }
    }
    __syncthreads();
    if (sflags[1]) bina1_body<1>(ei, attr, E, N, sflags[0], binned, cntm, locm,
                                 cnt, incl, cur, stage);
    else           bina1_body<0>(ei, attr, E, N, sflags[0], binned, cntm, locm,
                                 cnt, incl, cur, stage);
}

// per-bucket total = column sum of cntm
__global__ __launch_bounds__(256) void sumb_kernel(const int* __restrict__ cntm,
                                                   int* __restrict__ btot, int EB) {
    __shared__ int w[4];
    int B = blockIdx.x, tid = threadIdx.x;
    int s = 0;
    for (int j = tid; j < EB; j += 256) s += cntm[j * 256 + B];
    #pragma unroll
    for (int off = 1; off < 64; off <<= 1) s += __shfl_xor(s, off);
    if ((tid & 63) == 0) w[tid >> 6] = s;
    __syncthreads();
    if (tid == 0) btot[B] = w[0] + w[1] + w[2] + w[3];
}

// scan bucket totals -> bbase; rowptr[N] = E
__global__ void scanc_kernel(const int* __restrict__ btot, int* __restrict__ bbase,
                             int* __restrict__ rowptr, int NB, int N, int E) {
    __shared__ int s[256];
    int tid = threadIdx.x;
    int v = (tid < NB) ? btot[tid] : 0;
    s[tid] = v;
    __syncthreads();
    for (int off = 1; off < 256; off <<= 1) {
        int u = (tid >= off) ? s[tid - off] : 0;
        __syncthreads();
        s[tid] += u;
        __syncthreads();
    }
    if (tid < NB) bbase[tid] = s[tid] - v;
    if (tid == 0) { bbase[NB] = s[255]; rowptr[N] = E; }
}

// per-bucket: gather runs via directory, node-sort in LDS, emit rowptr + 4B csr
__global__ __launch_bounds__(256) void passb_kernel(const uint2* __restrict__ binned,
                                                    const int* __restrict__ cntm,
                                                    const int* __restrict__ locm,
                                                    const int* __restrict__ bbase,
                                                    int* __restrict__ rowptr,
                                                    unsigned* __restrict__ csr,
                                                    int N, int EB) {
    __shared__ int nc[256], incl[256], cur[256];
    __shared__ int cntl[EBMAX], locl[EBMAX];
    int B = blockIdx.x, tid = threadIdx.x;
    for (int j = tid; j < EB; j += 256) {
        cntl[j] = cntm[j * 256 + B];
        locl[j] = locm[j * 256 + B];
    }
    nc[tid] = 0;
    __syncthreads();
    for (int j = tid; j < EB; j += 256) {
        int c = cntl[j];
        const uint2* src = binned + (size_t)j * ACHUNK + locl[j];
        for (int i = 0; i < c; ++i)
            atomicAdd(&nc[(src[i].x >> 16) & 255], 1);
    }
    __syncthreads();
    incl[tid] = nc[tid];
    __syncthreads();
    for (int off = 1; off < 256; off <<= 1) {
        int u = (tid >= off) ? incl[tid - off] : 0;
        __syncthreads();
        incl[tid] += u;
        __syncthreads();
    }
    int base = bbase[B];
    int excl = incl[tid] - nc[tid];
    int node = (B << 8) + tid;
    if (node < N) rowptr[node] = base + excl;
    cur[tid] = excl;
    __syncthreads();
    for (int j = tid; j < EB; j += 256) {
        int c = cntl[j];
        const uint2* src = binned + (size_t)j * ACHUNK + locl[j];
        for (int i = 0; i < c; ++i) {
            uint2 r = src[i];
            int p = atomicAdd(&cur[(r.x >> 16) & 255], 1);
            csr[base + p] = r.y | (r.x & 0xFFFFu);
        }
    }
}

// ================= fallback CSR build (N > 65536 or EB > EBMAX) =================

__global__ void hist_kernel(const int* __restrict__ ei, const unsigned short* __restrict__ xu,
                            int E, int N, int* __restrict__ flags, int* __restrict__ cnt) {
    int is64 = calc_is64(ei);
    if (blockIdx.x == 0 && threadIdx.x == 0) {
        flags[0] = is64;
        flags[1] = calc_isf32(xu);
    }
    int e = blockIdx.x * blockDim.x + threadIdx.x;
    if (e >= E) return;
    atomicAdd(&cnt[ld_idx(ei, (long long)E + e, is64, N)], 1);
}

__global__ __launch_bounds__(256) void scan_partial(const int* __restrict__ cnt,
                                                    int* __restrict__ bsum, int N) {
    __shared__ int wsum[4];
    int b = blockIdx.x, tid = threadIdx.x;
    int base = b * SCAN_TILE + tid * 4;
    int4 v = make_int4(0, 0, 0, 0);
    if (base + 3 < N) v = *(const int4*)(cnt + base);
    else {
        if (base + 0 < N) v.x = cnt[base + 0];
        if (base + 1 < N) v.y = cnt[base + 1];
        if (base + 2 < N) v.z = cnt[base + 2];
    }
    int s = v.x + v.y + v.z + v.w;
    #pragma unroll
    for (int off = 1; off < 64; off <<= 1) s += __shfl_xor(s, off);
    if ((tid & 63) == 0) wsum[tid >> 6] = s;
    __syncthreads();
    if (tid == 0) bsum[b] = wsum[0] + wsum[1] + wsum[2] + wsum[3];
}

__global__ __launch_bounds__(256) void scan_final(int* __restrict__ cnt, int* __restrict__ rowptr,
                                                  const int* __restrict__ bsum, int N, int B) {
    __shared__ int tsum[256];
    __shared__ int bpre[256];
    int b = blockIdx.x, tid = threadIdx.x;
    bpre[tid] = (tid < B) ? bsum[tid] : 0;
    int base = b * SCAN_TILE + tid * 4;
    int4 v = make_int4(0, 0, 0, 0);
    if (base + 3 < N) v = *(const int4*)(cnt + base);
    else {
        if (base + 0 < N) v.x = cnt[base + 0];
        if (base + 1 < N) v.y = cnt[base + 1];
        if (base + 2 < N) v.z = cnt[base + 2];
    }
    tsum[tid] = v.x + v.y + v.z + v.w;
    __syncthreads();
    for (int off = 1; off < 256; off <<= 1) {
        int t = (tid >= off) ? tsum[tid - off] : 0;
        int u = (tid >= off) ? bpre[tid - off] : 0;
        __syncthreads();
        tsum[tid] += t;
        bpre[tid] += u;
        __syncthreads();
    }
    int blockpre = (b == 0) ? 0 : bpre[b - 1];
    int o0 = blockpre + ((tid == 0) ? 0 : tsum[tid - 1]);
    int o1 = o0 + v.x, o2 = o1 + v.y, o3 = o2 + v.z;
    if (base + 3 < N) {
        int4 o = make_int4(o0, o1, o2, o3);
        *(int4*)(rowptr + base) = o;
        *(int4*)(cnt + base) = o;
    } else {
        if (base + 0 < N) { rowptr[base + 0] = o0; cnt[base + 0] = o0; }
        if (base + 1 < N) { rowptr[base + 1] = o1; cnt[base + 1] = o1; }
        if (base + 2 < N) { rowptr[base + 2] = o2; cnt[base + 2] = o2; }
    }
    if (b == 0 && tid == 255) rowptr[N] = bpre[255];
}

template<int F32>
__device__ void scatter_body(const int* __restrict__ ei, const void* __restrict__ attr,
                             int E, int N, int is64, int* __restrict__ cursor,
                             uint2* __restrict__ csr) {
    int e = blockIdx.x * blockDim.x + threadIdx.x;
    if (e >= E) return;
    int d = ld_idx(ei, (long long)E + e, is64, N);
    int s = ld_idx(ei, (long long)e, is64, N);
    float av = ldf<F32>(attr, e);
    int pos = atomicAdd(&cursor[d], 1);
    csr[pos] = make_uint2((unsigned)s, __float_as_uint(av));
}

__global__ void scatter_kernel(const int* __restrict__ ei, const void* __restrict__ attr,
                               int E, int N, const int* __restrict__ flags,
                               int* __restrict__ cursor, uint2* __restrict__ csr) {
    if (flags[1]) scatter_body<1>(ei, attr, E, N, flags[0], cursor, csr);
    else          scatter_body<0>(ei, attr, E, N, flags[0], cursor, csr);
}

// ================= Layer-1 aggregation (r12 exact — best measured) =================

template<int F32, int P4>
__device__ void agg1_body(
    const int* __restrict__ rowptr, const void* __restrict__ csr,
    const void* __restrict__ x,
    const void* W1l, const void* b1l, const void* W1r, const void* b1r,
    const void* We1, const void* att1, const void* bias1, const void* g1v, const void* beta1,
    bf16* __restrict__ hout, int N) {
    int w0 = __builtin_amdgcn_readfirstlane((blockIdx.x * blockDim.x + threadIdx.x) >> 6);
    int NW = (gridDim.x * blockDim.x) >> 6;
    int lane = threadIdx.x & 63;
    int h = lane >> 4, q = lane & 15;
    int ja = h * 32 + q, jb = ja + 16;

    float wlaA = ldf<F32>(W1l, ja),      wlaB = ldf<F32>(W1l, jb);
    float wlbA = ldf<F32>(W1l, 128 + ja), wlbB = ldf<F32>(W1l, 128 + jb);
    float wraA = ldf<F32>(W1r, ja),      wraB = ldf<F32>(W1r, jb);
    float wrbA = ldf<F32>(W1r, 128 + ja), wrbB = ldf<F32>(W1r, 128 + jb);
    float blA = ldf<F32>(b1l, ja), blB = ldf<F32>(b1l, jb);
    float brA = ldf<F32>(b1r, ja), brB = ldf<F32>(b1r, jb);
    float weA = ldf<F32>(We1, ja), weB = ldf<F32>(We1, jb);
    float atA = ldf<F32>(att1, ja), atB = ldf<F32>(att1, jb);
    float aa4A = 0.4f * atA, aa4B = 0.4f * atB;
    float blbrA = blA + brA, blbrB = blB + brB;
    float P0 = 0.6f * red16(atA * wlaA + atB * wlaB);
    float P1 = 0.6f * red16(atA * wlbA + atB * wlbB);
    float Pw = 0.6f * red16(atA * weA + atB * weB);
    float Q0 = 0.6f * red16(atA * wraA + atB * wraB);
    float Q1 = 0.6f * red16(atA * wrbA + atB * wrbB);
    float Qc = 0.6f * red16(atA * blbrA + atB * blbrB);
    float biasA = ldf<F32>(bias1, q), biasB = ldf<F32>(bias1, q + 16);
    float gA = ldf<F32>(g1v, q), gB = ldf<F32>(g1v, q + 16);
    float beA = ldf<F32>(beta1, q), beB = ldf<F32>(beta1, q + 16);

    for (int n = w0; n < N; n += NW) {
        int beg = rowptr[n], end = rowptr[n + 1];
        float xd0, xd1;
        ldx<F32>(x, n, xd0, xd1);
        float cA = fmaf(xd0, wraA, fmaf(xd1, wrbA, blbrA));
        float cB = fmaf(xd0, wraB, fmaf(xd1, wrbB, blbrB));
        float Kn = fmaf(xd0, Q0, fmaf(xd1, Q1, Qc));
        float S = 0.f, Sx0 = 0.f, Sx1 = 0.f;

        auto edge = [&](float xs0, float xs1, float a) {
            float zA = fmaf(xs0, wlaA, fmaf(xs1, wlbA, fmaf(a, weA, cA)));
            float zB = fmaf(xs0, wlaB, fmaf(xs1, wlbB, fmaf(a, weB, cB)));
            float pabs = red16(fmaf(fabsf(zA), aa4A, fabsf(zB) * aa4B));
            float p = sclamp(fmaf(xs0, P0, fmaf(xs1, P1, fmaf(a, Pw, Kn))) + pabs, 60.f);
            float e = __expf(p);
            S += e;
            Sx0 = fmaf(e, xs0, Sx0);
            Sx1 = fmaf(e, xs1, Sx1);
        };

        int k = beg;
        for (; k + 4 <= end; k += 4) {
            int s0, s1, s2, s3;
            float a0, a1, a2, a3;
            ldrec<P4>(csr, k, s0, a0);
            ldrec<P4>(csr, k + 1, s1, a1);
            ldrec<P4>(csr, k + 2, s2, a2);
            ldrec<P4>(csr, k + 3, s3, a3);
            float p0, p1, q0, q1, r0, r1, t0, t1;
            ldx<F32>(x, s0, p0, p1);
            ldx<F32>(x, s1, q0, q1);
            ldx<F32>(x, s2, r0, r1);
            ldx<F32>(x, s3, t0, t1);
            edge(p0, p1, a0);
            edge(q0, q1, a1);
            edge(r0, r1, a2);
            edge(t0, t1, a3);
        }
        for (; k < end; ++k) {
            int s0; float a0;
            ldrec<P4>(csr, k, s0, a0);
            float p0, p1;
            ldx<F32>(x, s0, p0, p1);
            edge(p0, p1, a0);
        }

        float inv = 1.0f / (S + 1e-16f);
        float R = S * inv, U0 = Sx0 * inv, U1 = Sx1 * inv;
        float outA = fmaf(U0, wlaA, fmaf(U1, wlbA, R * blA));
        float outB = fmaf(U0, wlaB, fmaf(U1, wlbB, R * blB));
        outA += __shfl_xor(outA, 16); outA += __shfl_xor(outA, 32);
        outB += __shfl_xor(outB, 16); outB += __shfl_xor(outB, 32);
        float valA = fmaf(0.25f, outA, biasA);
        float valB = fmaf(0.25f, outB, biasB);
        float mu = red16(valA + valB) * (1.f / 32.f);
        float dA = valA - mu, dB = valB - mu;
        float var = red16(dA * dA + dB * dB) * (1.f / 32.f);
        float rs = rsqrtf(var + LN_EPS);
        float yA = fmaf(dA * rs, gA, beA);
        float yB = fmaf(dB * rs, gB, beB);
        float hA = yA > 0.f ? yA : expm1f(yA);
        float hB = yB > 0.f ? yB : expm1f(yB);
        if (lane < 16) {
            hout[n * 32 + q]      = f2b(hA);
            hout[n * 32 + 16 + q] = f2b(hB);
        }
    }
}

template<int P4>
__global__ __launch_bounds__(256) void agg1_kernel(
    const int* __restrict__ flags,
    const int* __restrict__ rowptr, const void* __restrict__ csr,
    const void* __restrict__ x,
    const void* W1l, const void* b1l, const void* W1r, const void* b1r,
    const void* We1, const void* att1, const void* bias1, const void* g1v, const void* beta1,
    bf16* __restrict__ hout, int N) {
    if (flags[1]) agg1_body<1, P4>(rowptr, csr, x, W1l, b1l, W1r, b1r,
                                   We1, att1, bias1, g1v, beta1, hout, N);
    else          agg1_body<0, P4>(rowptr, csr, x, W1l, b1l, W1r, b1r,
                                   We1, att1, bias1, g1v, beta1, hout, N);
}

// ================= Layer-2 node transform, in-place over hbuf =================

template<int F32>
__device__ void node2_body(bf16* __restrict__ hbuf, float* wl, float* wr,
                           const void* W2l, const void* b2l, const void* W2r, const void* b2r,
                           int N) {
    __shared__ float bl[16], br[16];
    int tid = threadIdx.x;
    for (int i = tid; i < 512; i += 256) { wl[i] = ldf<F32>(W2l, i); wr[i] = ldf<F32>(W2r, i); }
    if (tid < 16) { bl[tid] = ldf<F32>(b2l, tid); br[tid] = ldf<F32>(b2r, tid); }
    __syncthreads();
    int n = blockIdx.x * blockDim.x + tid;
    if (n >= N) return;
    float hv[32];
    #pragma unroll
    for (int c = 0; c < 32; ++c) hv[c] = b2f(hbuf[n * 32 + c]);
    float accl[16], accr[16];
    #pragma unroll
    for (int o = 0; o < 16; ++o) { accl[o] = bl[o]; accr[o] = br[o]; }
    #pragma unroll
    for (int c = 0; c < 32; ++c) {
        #pragma unroll
        for (int o = 0; o < 16; ++o) {
            accl[o] = fmaf(hv[c], wl[c * 16 + o], accl[o]);
            accr[o] = fmaf(hv[c], wr[c * 16 + o], accr[o]);
        }
    }
    #pragma unroll
    for (int o = 0; o < 16; ++o) {
        hbuf[n * 32 + o]      = f2b(accl[o]);   // h2l
        hbuf[n * 32 + 16 + o] = f2b(accr[o]);   // h2r
    }
}

__global__ __launch_bounds__(256) void node2_kernel(
    const int* __restrict__ flags, bf16* __restrict__ hbuf,
    const void* W2l, const void* b2l, const void* W2r, const void* b2r, int N) {
    __shared__ float wl[512], wr[512];
    if (flags[1]) node2_body<1>(hbuf, wl, wr, W2l, b2l, W2r, b2r, N);
    else          node2_body<0>(hbuf, wl, wr, W2l, b2l, W2r, b2r, N);
}

// ================= Layer-2 aggregation (r12 exact) =================

template<int F32, int P4>
__device__ void agg2_body(
    const int* __restrict__ rowptr, const void* __restrict__ csr,
    const bf16* __restrict__ h2,
    const void* We2, const void* att2, const void* bias2, const void* g2v, const void* beta2,
    void* __restrict__ out, int N) {
    int w0 = __builtin_amdgcn_readfirstlane((blockIdx.x * blockDim.x + threadIdx.x) >> 6);
    int NW = (gridDim.x * blockDim.x) >> 6;
    int lane = threadIdx.x & 63;
    int g = lane >> 4, t = lane & 15;

    float we = ldf<F32>(We2, t), at = ldf<F32>(att2, t);
    float bia = ldf<F32>(bias2, t), gg = ldf<F32>(g2v, t), bb = ldf<F32>(beta2, t);

    for (int n = w0; n < N; n += NW) {
        int beg = rowptr[n], end = rowptr[n + 1];
        float xr = b2f(h2[n * 32 + 16 + t]);

        float S = 0.f, A = 0.f;
        auto edge = [&](float v, float a) {
            float m = fmaf(a, we, v + xr);
            m = fmaxf(m, NEG_SLOPE * m);
            float p = sclamp(red16(m * at), 60.f);
            float e = __expf(p);
            S += e;
            A = fmaf(e, v, A);
        };
        int k = beg + g;
        for (; k + 4 < end; k += 8) {
            int s0, s1; float a0, a1;
            ldrec<P4>(csr, k, s0, a0);
            ldrec<P4>(csr, k + 4, s1, a1);
            float v0 = b2f(h2[s0 * 32 + t]);
            float v1 = b2f(h2[s1 * 32 + t]);
            edge(v0, a0);
            edge(v1, a1);
        }
        if (k < end) {
            int s0; float a0;
            ldrec<P4>(csr, k, s0, a0);
            edge(b2f(h2[s0 * 32 + t]), a0);
        }
        S += __shfl_xor(S, 16); S += __shfl_xor(S, 32);
        A += __shfl_xor(A, 16); A += __shfl_xor(A, 32);
        float val = A / (S + 1e-16f) + bia;

        float mu = red16(val) * (1.f / 16.f);
        float d = val - mu;
        float var = red16(d * d) * (1.f / 16.f);
        float y = fmaf(d * rsqrtf(var + LN_EPS), gg, bb);
        if (lane < 16) {
            if (F32) ((float*)out)[n * 16 + t] = y;
            else     ((bf16*)out)[n * 16 + t] = f2b(y);
        }
    }
}

template<int P4>
__global__ __launch_bounds__(256) void agg2_kernel(
    const int* __restrict__ flags,
    const int* __restrict__ rowptr, const void* __restrict__ csr,
    const bf16* __restrict__ h2,
    const void* We2, const void* att2, const void* bias2, const void* g2v, const void* beta2,
    void* __restrict__ out, int N) {
    if (flags[1]) agg2_body<1, P4>(rowptr, csr, h2, We2, att2, bias2, g2v, beta2, out, N);
    else          agg2_body<0, P4>(rowptr, csr, h2, We2, att2, bias2, g2v, beta2, out, N);
}

// ================= host =================

static inline size_t align256(size_t x) { return (x + 255) & ~size_t(255); }

extern "C" void kernel_launch(void* const* d_in, const int* in_sizes, int n_in,
                              void* d_out, int out_size, void* d_ws, size_t ws_size,
                              hipStream_t stream) {
    const void* x     = d_in[0];
    const int*  ei    = (const int*)d_in[1];
    const void* eattr = d_in[2];
    const void* W1l   = d_in[3];
    const void* b1l   = d_in[4];
    const void* W1r   = d_in[5];
    const void* b1r   = d_in[6];
    const void* We1   = d_in[7];
    const void* att1  = d_in[8];
    const void* bias1 = d_in[9];
    const void* g1    = d_in[10];
    const void* beta1 = d_in[11];
    const void* W2l   = d_in[12];
    const void* b2l   = d_in[13];
    const void* W2r   = d_in[14];
    const void* b2r   = d_in[15];
    const void* We2   = d_in[16];
    const void* att2  = d_in[17];
    const void* bias2 = d_in[18];
    const void* g2    = d_in[19];
    const void* beta2 = d_in[20];

    const int N = in_sizes[0] / 2;   // x is (N,2)
    const int E = in_sizes[2];       // edge_attr is (E,1)
    const int EB = (E + ACHUNK - 1) / ACHUNK;
    const int NB = (N + 255) >> 8;
    const bool p4 = (N <= 65536) && (EB <= EBMAX);

    char* ws = (char*)d_ws;
    size_t off = 0;
    int* flags  = (int*)(ws + off); off += align256(sizeof(int) * 2);
    int* cntm   = (int*)(ws + off); off += align256(sizeof(int) * (size_t)EB * 256);  // also bsum (fallback)
    int* locm   = (int*)(ws + off); off += align256(sizeof(int) * (size_t)EB * 256);
    int* btot   = (int*)(ws + off); off += align256(sizeof(int) * 256);
    int* bbase  = (int*)(ws + off); off += align256(sizeof(int) * 257);
    int* rowptr = (int*)(ws + off); off += align256(sizeof(int) * (size_t)(N + 1));
    void* csr   = (void*)(ws + off); off += align256((p4 ? 4u : 8u) * (size_t)E);
    char* big   = (ws + off);
    uint2* binned = (uint2*)big;                     // EB*ACHUNK*8 B, dead after passb
    bf16*  hbuf   = (bf16*)big;                      // N*32 bf16, written after binned dies

    if (p4) {
        bina1_kernel<<<EB, 256, 0, stream>>>(ei, eattr, (const unsigned short*)x,
                                             E, N, flags, binned, cntm, locm);
        sumb_kernel<<<NB, 256, 0, stream>>>(cntm, btot, EB);
        scanc_kernel<<<1, 256, 0, stream>>>(btot, bbase, rowptr, NB, N, E);
        passb_kernel<<<NB, 256, 0, stream>>>(binned, cntm, locm, bbase, rowptr,
                                             (unsigned*)csr, N, EB);
    } else {
        int* cnt = (int*)big;
        hbuf = (bf16*)(big + align256(sizeof(int) * (size_t)N));
        const int B = (N + SCAN_TILE - 1) / SCAN_TILE;
        hipMemsetAsync(cnt, 0, sizeof(int) * (size_t)N, stream);
        hist_kernel<<<(E + 255) / 256, 256, 0, stream>>>(ei, (const unsigned short*)x, E, N, flags, cnt);
        scan_partial<<<B, 256, 0, stream>>>(cnt, cntm, N);
        scan_final<<<B, 256, 0, stream>>>(cnt, rowptr, cntm, N, B);
        scatter_kernel<<<(E + 255) / 256, 256, 0, stream>>>(ei, eattr, E, N, flags, cnt, (uint2*)csr);
    }

    if (p4) agg1_kernel<1><<<2048, 256, 0, stream>>>(flags, rowptr, csr, x,
                                                     W1l, b1l, W1r, b1r, We1, att1,
                                                     bias1, g1, beta1, hbuf, N);
    else    agg1_kernel<0><<<2048, 256, 0, stream>>>(flags, rowptr, csr, x,
                                                     W1l, b1l, W1r, b1r, We1, att1,
                                                     bias1, g1, beta1, hbuf, N);

    node2_kernel<<<(N + 255) / 256, 256, 0, stream>>>(flags, hbuf, W2l, b2l, W2r, b2r, N);

    if (p4) agg2_kernel<1><<<2048, 256, 0, stream>>>(flags, rowptr, csr, hbuf,
                                                     We2, att2, bias2, g2, beta2, d_out, N);
    else    agg2_kernel<0><<<2048, 256, 0, stream>>>(flags, rowptr, csr, hbuf,
                                                     We2, att2, bias2, g2, beta2, d_out, N);
}

// Round 14
// 209.162 us; speedup vs baseline: 1.1232x; 1.0471x over previous
//
#include <hip/hip_runtime.h>
#include <hip/hip_bf16.h>
#include <math.h>

typedef __hip_bfloat16 bf16;

__device__ __forceinline__ float b2f(bf16 v) { return __bfloat162float(v); }
__device__ __forceinline__ bf16  f2b(float v) { return __float2bfloat16(v); }

template<int F32>
__device__ __forceinline__ float ldf(const void* p, int i) {
    return F32 ? ((const float*)p)[i] : b2f(((const bf16*)p)[i]);
}
template<int F32>
__device__ __forceinline__ void ldx(const void* x, int s, float& x0, float& x1) {
    if (F32) { float2 v = ((const float2*)x)[s]; x0 = v.x; x1 = v.y; }
    else {
        unsigned u = ((const unsigned*)x)[s];
        x0 = __uint_as_float((u & 0xFFFFu) << 16);
        x1 = __uint_as_float(u & 0xFFFF0000u);
    }
}
__device__ __forceinline__ unsigned f2b_hi(float f) {
    unsigned u = __float_as_uint(f);
    u += 0x7FFFu + ((u >> 16) & 1u);
    return u & 0xFFFF0000u;
}
template<int P4>
__device__ __forceinline__ void ldrec(const void* csr, int k, int& s, float& a) {
    if (P4) {
        unsigned u = ((const unsigned*)csr)[k];
        s = (int)(u & 0xFFFFu);
        a = __uint_as_float(u & 0xFFFF0000u);
    } else {
        uint2 r = ((const uint2*)csr)[k];
        s = (int)r.x;
        a = __uint_as_float(r.y);
    }
}
__device__ __forceinline__ float sclamp(float v, float lim) {
    return fminf(fmaxf(v, -lim), lim);
}
template<int CTRL>
__device__ __forceinline__ float dpp_add(float v) {
    int t = __builtin_amdgcn_update_dpp(0, __float_as_int(v), CTRL, 0xF, 0xF, true);
    return v + __int_as_float(t);
}
__device__ __forceinline__ float red16(float v) {
    v = dpp_add<0xB1>(v);
    v = dpp_add<0x4E>(v);
    v = dpp_add<0x124>(v);
    v = dpp_add<0x128>(v);
    return v;
}

#define NEG_SLOPE 0.2f
#define LN_EPS 1e-5f
#define SCAN_TILE 1024
#define ACHUNK 2048     // edges per build block (8 per thread)
#define EBMAX 512       // max build blocks supported by passb's LDS directory
#define SCAP 8192       // passb LDS stage capacity (edges per bucket)

__device__ __forceinline__ int ld_idx(const int* ei, long long pos, int is64, int N) {
    int v = is64 ? ei[2 * pos] : ei[pos];
    return min(max(v, 0), N - 1);
}
__device__ __forceinline__ int calc_is64(const int* ei) {
    int hi = 0, nz = 0;
    #pragma unroll
    for (int i = 0; i < 8; ++i) { hi |= ei[2 * i + 1]; nz |= ei[2 * i]; }
    return (hi == 0 && nz != 0) ? 1 : 0;
}
__device__ __forceinline__ int calc_isf32(const unsigned short* xu) {
    int pl = 0;
    for (int i = 0; i < 32; ++i) {
        unsigned ex = (xu[2 * i] >> 7) & 0xFF;
        if (ex >= 100 && ex <= 140) pl++;
    }
    return (pl >= 24) ? 0 : 1;
}

// ====== one-pass bucketed build (N<=65536, EB<=512): 5B intermediate records ======
// Block b bins its 2048 edges by bucket (dst>>8) in LDS, writes bucket-grouped runs
// to binned4 (attr_hi|src, final csr format) + binnedb (dst&255), plus directory
// cntm/locm [block-major].

template<int F32>
__device__ void bina1_body(const int* __restrict__ ei, const void* __restrict__ attr,
                           int E, int N, int is64,
                           unsigned* __restrict__ binned4, unsigned char* __restrict__ binnedb,
                           int* __restrict__ cntm, int* __restrict__ locm,
                           int* cnt, int* incl, int* cur,
                           unsigned* stage4, unsigned char* stageb) {
    int tid = threadIdx.x, b = blockIdx.x;
    cnt[tid] = 0;
    __syncthreads();
    int i0 = b * ACHUNK;
    int iend = min(i0 + ACHUNK, E);
    unsigned rec[8]; int bk[8], lo[8];
    #pragma unroll
    for (int r = 0; r < 8; ++r) {
        int i = i0 + tid + r * 256;
        bk[r] = -1;
        if (i < iend) {
            int d = ld_idx(ei, (long long)E + i, is64, N);
            int s = ld_idx(ei, (long long)i, is64, N);
            float a = ldf<F32>(attr, i);
            rec[r] = f2b_hi(a) | (unsigned)s;
            bk[r] = d >> 8;
            lo[r] = d & 255;
            atomicAdd(&cnt[bk[r]], 1);
        }
    }
    __syncthreads();
    incl[tid] = cnt[tid];
    __syncthreads();
    for (int off = 1; off < 256; off <<= 1) {
        int u = (tid >= off) ? incl[tid - off] : 0;
        __syncthreads();
        incl[tid] += u;
        __syncthreads();
    }
    cur[tid] = incl[tid] - cnt[tid];
    __syncthreads();
    #pragma unroll
    for (int r = 0; r < 8; ++r) {
        if (bk[r] >= 0) {
            int p = atomicAdd(&cur[bk[r]], 1);
            stage4[p] = rec[r];
            stageb[p] = (unsigned char)lo[r];
        }
    }
    __syncthreads();
    int n = iend - i0;
    for (int i = tid; i < n; i += 256) {               // dense coalesced region writes
        binned4[(size_t)b * ACHUNK + i] = stage4[i];
        binnedb[(size_t)b * ACHUNK + i] = stageb[i];
    }
    cntm[b * 256 + tid] = cnt[tid];
    locm[b * 256 + tid] = incl[tid] - cnt[tid];
}

__global__ __launch_bounds__(256) void bina1_kernel(const int* __restrict__ ei,
                                                    const void* __restrict__ attr,
                                                    const unsigned short* __restrict__ xu,
                                                    int E, int N, int* __restrict__ flags,
                                                    unsigned* __restrict__ binned4,
                                                    unsigned char* __restrict__ binnedb,
                                                    int* __restrict__ cntm,
                                                    int* __restrict__ locm) {
    __shared__ int cnt[256], incl[256], cur[256];
    __shared__ unsigned stage4[ACHUNK];
    __shared__ unsigned char stageb[ACHUNK];
    __shared__ int sflags[2];
    if (threadIdx.x == 0) {
        sflags[0] = calc_is64(ei);
        sflags[1] = calc_isf32(xu);
        if (blockIdx.x == 0) { flags[0] = sflags[0]; flags[1] = sflags[1]; }
    }
    __syncthreads();
    if (sflags[1]) bina1_body<1>(ei, attr, E, N, sflags[0], binned4, binnedb, cntm, locm,
                                 cnt, incl, cur, stage4, stageb);
    else           bina1_body<0>(ei, attr, E, N, sflags[0], binned4, binnedb, cntm, locm,
                                 cnt, incl, cur, stage4, stageb);
}

// per-bucket total = column sum of cntm; also writes rowptr[N]=E
__global__ __launch_bounds__(256) void sumb_kernel(const int* __restrict__ cntm,
                                                   int* __restrict__ btot, int EB,
                                                   int* __restrict__ rowptr, int N, int E) {
    __shared__ int w[4];
    int B = blockIdx.x, tid = threadIdx.x;
    if (B == 0 && tid == 0) rowptr[N] = E;
    int s = 0;
    for (int j = tid; j < EB; j += 256) s += cntm[j * 256 + B];
    #pragma unroll
    for (int off = 1; off < 64; off <<= 1) s += __shfl_xor(s, off);
    if ((tid & 63) == 0) w[tid >> 6] = s;
    __syncthreads();
    if (tid == 0) btot[B] = w[0] + w[1] + w[2] + w[3];
}

// per-bucket: redundant btot scan -> base; gather runs into LDS (single global read),
// node-count, scan, emit rowptr + place csr from LDS. Overflow -> two-pass global.
__global__ __launch_bounds__(256) void passb_kernel(const unsigned* __restrict__ binned4,
                                                    const unsigned char* __restrict__ binnedb,
                                                    const int* __restrict__ cntm,
                                                    const int* __restrict__ locm,
                                                    const int* __restrict__ btot,
                                                    int* __restrict__ rowptr,
                                                    unsigned* __restrict__ csr,
                                                    int N, int EB, int NB) {
    __shared__ int nc[256], incl[256], cur[256], bsc[256], ebase[256];
    __shared__ int cntl[EBMAX], locl[EBMAX];
    __shared__ unsigned stage4[SCAP];
    __shared__ unsigned char stageb[SCAP];
    __shared__ int stageCnt;
    int B = blockIdx.x, tid = threadIdx.x;
    int v = (tid < NB) ? btot[tid] : 0;
    bsc[tid] = v;
    nc[tid] = 0;
    if (tid == 0) stageCnt = 0;
    for (int j = tid; j < EB; j += 256) {
        cntl[j] = cntm[j * 256 + B];
        locl[j] = locm[j * 256 + B];
    }
    __syncthreads();
    for (int off = 1; off < 256; off <<= 1) {
        int u = (tid >= off) ? bsc[tid - off] : 0;
        __syncthreads();
        bsc[tid] += u;
        __syncthreads();
    }
    ebase[tid] = bsc[tid] - v;
    __syncthreads();
    int base = ebase[B];
    int cntb = btot[B];
    bool fit = (cntb <= SCAP);

    if (fit) {
        for (int j = tid; j < EB; j += 256) {
            int c = cntl[j];
            if (c > 0) {
                int p = atomicAdd(&stageCnt, c);
                const unsigned* s4 = binned4 + (size_t)j * ACHUNK + locl[j];
                const unsigned char* sb = binnedb + (size_t)j * ACHUNK + locl[j];
                for (int i = 0; i < c; ++i) {
                    unsigned r4 = s4[i];
                    unsigned char l = sb[i];
                    stage4[p + i] = r4;
                    stageb[p + i] = l;
                    atomicAdd(&nc[l], 1);
                }
            }
        }
    } else {
        for (int j = tid; j < EB; j += 256) {
            int c = cntl[j];
            const unsigned char* sb = binnedb + (size_t)j * ACHUNK + locl[j];
            for (int i = 0; i < c; ++i) atomicAdd(&nc[sb[i]], 1);
        }
    }
    __syncthreads();
    incl[tid] = nc[tid];
    __syncthreads();
    for (int off = 1; off < 256; off <<= 1) {
        int u = (tid >= off) ? incl[tid - off] : 0;
        __syncthreads();
        incl[tid] += u;
        __syncthreads();
    }
    int excl = incl[tid] - nc[tid];
    int node = (B << 8) + tid;
    if (node < N) rowptr[node] = base + excl;
    cur[tid] = excl;
    __syncthreads();
    if (fit) {
        for (int i = tid; i < cntb; i += 256) {
            int l = stageb[i];
            int p = atomicAdd(&cur[l], 1);
            csr[base + p] = stage4[i];
        }
    } else {
        for (int j = tid; j < EB; j += 256) {
            int c = cntl[j];
            const unsigned* s4 = binned4 + (size_t)j * ACHUNK + locl[j];
            const unsigned char* sb = binnedb + (size_t)j * ACHUNK + locl[j];
            for (int i = 0; i < c; ++i) {
                int p = atomicAdd(&cur[sb[i]], 1);
                csr[base + p] = s4[i];
            }
        }
    }
}

// ================= fallback CSR build (N > 65536 or EB > EBMAX) =================

__global__ void hist_kernel(const int* __restrict__ ei, const unsigned short* __restrict__ xu,
                            int E, int N, int* __restrict__ flags, int* __restrict__ cnt) {
    int is64 = calc_is64(ei);
    if (blockIdx.x == 0 && threadIdx.x == 0) {
        flags[0] = is64;
        flags[1] = calc_isf32(xu);
    }
    int e = blockIdx.x * blockDim.x + threadIdx.x;
    if (e >= E) return;
    atomicAdd(&cnt[ld_idx(ei, (long long)E + e, is64, N)], 1);
}

__global__ __launch_bounds__(256) void scan_partial(const int* __restrict__ cnt,
                                                    int* __restrict__ bsum, int N) {
    __shared__ int wsum[4];
    int b = blockIdx.x, tid = threadIdx.x;
    int base = b * SCAN_TILE + tid * 4;
    int4 v = make_int4(0, 0, 0, 0);
    if (base + 3 < N) v = *(const int4*)(cnt + base);
    else {
        if (base + 0 < N) v.x = cnt[base + 0];
        if (base + 1 < N) v.y = cnt[base + 1];
        if (base + 2 < N) v.z = cnt[base + 2];
    }
    int s = v.x + v.y + v.z + v.w;
    #pragma unroll
    for (int off = 1; off < 64; off <<= 1) s += __shfl_xor(s, off);
    if ((tid & 63) == 0) wsum[tid >> 6] = s;
    __syncthreads();
    if (tid == 0) bsum[b] = wsum[0] + wsum[1] + wsum[2] + wsum[3];
}

__global__ __launch_bounds__(256) void scan_final(int* __restrict__ cnt, int* __restrict__ rowptr,
                                                  const int* __restrict__ bsum, int N, int B) {
    __shared__ int tsum[256];
    __shared__ int bpre[256];
    int b = blockIdx.x, tid = threadIdx.x;
    bpre[tid] = (tid < B) ? bsum[tid] : 0;
    int base = b * SCAN_TILE + tid * 4;
    int4 v = make_int4(0, 0, 0, 0);
    if (base + 3 < N) v = *(const int4*)(cnt + base);
    else {
        if (base + 0 < N) v.x = cnt[base + 0];
        if (base + 1 < N) v.y = cnt[base + 1];
        if (base + 2 < N) v.z = cnt[base + 2];
    }
    tsum[tid] = v.x + v.y + v.z + v.w;
    __syncthreads();
    for (int off = 1; off < 256; off <<= 1) {
        int t = (tid >= off) ? tsum[tid - off] : 0;
        int u = (tid >= off) ? bpre[tid - off] : 0;
        __syncthreads();
        tsum[tid] += t;
        bpre[tid] += u;
        __syncthreads();
    }
    int blockpre = (b == 0) ? 0 : bpre[b - 1];
    int o0 = blockpre + ((tid == 0) ? 0 : tsum[tid - 1]);
    int o1 = o0 + v.x, o2 = o1 + v.y, o3 = o2 + v.z;
    if (base + 3 < N) {
        int4 o = make_int4(o0, o1, o2, o3);
        *(int4*)(rowptr + base) = o;
        *(int4*)(cnt + base) = o;
    } else {
        if (base + 0 < N) { rowptr[base + 0] = o0; cnt[base + 0] = o0; }
        if (base + 1 < N) { rowptr[base + 1] = o1; cnt[base + 1] = o1; }
        if (base + 2 < N) { rowptr[base + 2] = o2; cnt[base + 2] = o2; }
    }
    if (b == 0 && tid == 255) rowptr[N] = bpre[255];
}

template<int F32>
__device__ void scatter_body(const int* __restrict__ ei, const void* __restrict__ attr,
                             int E, int N, int is64, int* __restrict__ cursor,
                             uint2* __restrict__ csr) {
    int e = blockIdx.x * blockDim.x + threadIdx.x;
    if (e >= E) return;
    int d = ld_idx(ei, (long long)E + e, is64, N);
    int s = ld_idx(ei, (long long)e, is64, N);
    float av = ldf<F32>(attr, e);
    int pos = atomicAdd(&cursor[d], 1);
    csr[pos] = make_uint2((unsigned)s, __float_as_uint(av));
}

__global__ void scatter_kernel(const int* __restrict__ ei, const void* __restrict__ attr,
                               int E, int N, const int* __restrict__ flags,
                               int* __restrict__ cursor, uint2* __restrict__ csr) {
    if (flags[1]) scatter_body<1>(ei, attr, E, N, flags[0], cursor, csr);
    else          scatter_body<0>(ei, attr, E, N, flags[0], cursor, csr);
}

// ================= Layer-1 aggregation (r12 exact — best measured) =================

template<int F32, int P4>
__device__ void agg1_body(
    const int* __restrict__ rowptr, const void* __restrict__ csr,
    const void* __restrict__ x,
    const void* W1l, const void* b1l, const void* W1r, const void* b1r,
    const void* We1, const void* att1, const void* bias1, const void* g1v, const void* beta1,
    bf16* __restrict__ hout, int N) {
    int w0 = __builtin_amdgcn_readfirstlane((blockIdx.x * blockDim.x + threadIdx.x) >> 6);
    int NW = (gridDim.x * blockDim.x) >> 6;
    int lane = threadIdx.x & 63;
    int h = lane >> 4, q = lane & 15;
    int ja = h * 32 + q, jb = ja + 16;

    float wlaA = ldf<F32>(W1l, ja),      wlaB = ldf<F32>(W1l, jb);
    float wlbA = ldf<F32>(W1l, 128 + ja), wlbB = ldf<F32>(W1l, 128 + jb);
    float wraA = ldf<F32>(W1r, ja),      wraB = ldf<F32>(W1r, jb);
    float wrbA = ldf<F32>(W1r, 128 + ja), wrbB = ldf<F32>(W1r, 128 + jb);
    float blA = ldf<F32>(b1l, ja), blB = ldf<F32>(b1l, jb);
    float brA = ldf<F32>(b1r, ja), brB = ldf<F32>(b1r, jb);
    float weA = ldf<F32>(We1, ja), weB = ldf<F32>(We1, jb);
    float atA = ldf<F32>(att1, ja), atB = ldf<F32>(att1, jb);
    float aa4A = 0.4f * atA, aa4B = 0.4f * atB;
    float blbrA = blA + brA, blbrB = blB + brB;
    float P0 = 0.6f * red16(atA * wlaA + atB * wlaB);
    float P1 = 0.6f * red16(atA * wlbA + atB * wlbB);
    float Pw = 0.6f * red16(atA * weA + atB * weB);
    float Q0 = 0.6f * red16(atA * wraA + atB * wraB);
    float Q1 = 0.6f * red16(atA * wrbA + atB * wrbB);
    float Qc = 0.6f * red16(atA * blbrA + atB * blbrB);
    float biasA = ldf<F32>(bias1, q), biasB = ldf<F32>(bias1, q + 16);
    float gA = ldf<F32>(g1v, q), gB = ldf<F32>(g1v, q + 16);
    float beA = ldf<F32>(beta1, q), beB = ldf<F32>(beta1, q + 16);

    for (int n = w0; n < N; n += NW) {
        int beg = rowptr[n], end = rowptr[n + 1];
        float xd0, xd1;
        ldx<F32>(x, n, xd0, xd1);
        float cA = fmaf(xd0, wraA, fmaf(xd1, wrbA, blbrA));
        float cB = fmaf(xd0, wraB, fmaf(xd1, wrbB, blbrB));
        float Kn = fmaf(xd0, Q0, fmaf(xd1, Q1, Qc));
        float S = 0.f, Sx0 = 0.f, Sx1 = 0.f;

        auto edge = [&](float xs0, float xs1, float a) {
            float zA = fmaf(xs0, wlaA, fmaf(xs1, wlbA, fmaf(a, weA, cA)));
            float zB = fmaf(xs0, wlaB, fmaf(xs1, wlbB, fmaf(a, weB, cB)));
            float pabs = red16(fmaf(fabsf(zA), aa4A, fabsf(zB) * aa4B));
            float p = sclamp(fmaf(xs0, P0, fmaf(xs1, P1, fmaf(a, Pw, Kn))) + pabs, 60.f);
            float e = __expf(p);
            S += e;
            Sx0 = fmaf(e, xs0, Sx0);
            Sx1 = fmaf(e, xs1, Sx1);
        };

        int k = beg;
        for (; k + 4 <= end; k += 4) {
            int s0, s1, s2, s3;
            float a0, a1, a2, a3;
            ldrec<P4>(csr, k, s0, a0);
            ldrec<P4>(csr, k + 1, s1, a1);
            ldrec<P4>(csr, k + 2, s2, a2);
            ldrec<P4>(csr, k + 3, s3, a3);
            float p0, p1, q0, q1, r0, r1, t0, t1;
            ldx<F32>(x, s0, p0, p1);
            ldx<F32>(x, s1, q0, q1);
            ldx<F32>(x, s2, r0, r1);
            ldx<F32>(x, s3, t0, t1);
            edge(p0, p1, a0);
            edge(q0, q1, a1);
            edge(r0, r1, a2);
            edge(t0, t1, a3);
        }
        for (; k < end; ++k) {
            int s0; float a0;
            ldrec<P4>(csr, k, s0, a0);
            float p0, p1;
            ldx<F32>(x, s0, p0, p1);
            edge(p0, p1, a0);
        }

        float inv = 1.0f / (S + 1e-16f);
        float R = S * inv, U0 = Sx0 * inv, U1 = Sx1 * inv;
        float outA = fmaf(U0, wlaA, fmaf(U1, wlbA, R * blA));
        float outB = fmaf(U0, wlaB, fmaf(U1, wlbB, R * blB));
        outA += __shfl_xor(outA, 16); outA += __shfl_xor(outA, 32);
        outB += __shfl_xor(outB, 16); outB += __shfl_xor(outB, 32);
        float valA = fmaf(0.25f, outA, biasA);
        float valB = fmaf(0.25f, outB, biasB);
        float mu = red16(valA + valB) * (1.f / 32.f);
        float dA = valA - mu, dB = valB - mu;
        float var = red16(dA * dA + dB * dB) * (1.f / 32.f);
        float rs = rsqrtf(var + LN_EPS);
        float yA = fmaf(dA * rs, gA, beA);
        float yB = fmaf(dB * rs, gB, beB);
        float hA = yA > 0.f ? yA : expm1f(yA);
        float hB = yB > 0.f ? yB : expm1f(yB);
        if (lane < 16) {
            hout[n * 32 + q]      = f2b(hA);
            hout[n * 32 + 16 + q] = f2b(hB);
        }
    }
}

template<int P4>
__global__ __launch_bounds__(256) void agg1_kernel(
    const int* __restrict__ flags,
    const int* __restrict__ rowptr, const void* __restrict__ csr,
    const void* __restrict__ x,
    const void* W1l, const void* b1l, const void* W1r, const void* b1r,
    const void* We1, const void* att1, const void* bias1, const void* g1v, const void* beta1,
    bf16* __restrict__ hout, int N) {
    if (flags[1]) agg1_body<1, P4>(rowptr, csr, x, W1l, b1l, W1r, b1r,
                                   We1, att1, bias1, g1v, beta1, hout, N);
    else          agg1_body<0, P4>(rowptr, csr, x, W1l, b1l, W1r, b1r,
                                   We1, att1, bias1, g1v, beta1, hout, N);
}

// ================= Layer-2 node transform, in-place over hbuf =================

template<int F32>
__device__ void node2_body(bf16* __restrict__ hbuf, float* wl, float* wr,
                           const void* W2l, const void* b2l, const void* W2r, const void* b2r,
                           int N) {
    __shared__ float bl[16], br[16];
    int tid = threadIdx.x;
    for (int i = tid; i < 512; i += 256) { wl[i] = ldf<F32>(W2l, i); wr[i] = ldf<F32>(W2r, i); }
    if (tid < 16) { bl[tid] = ldf<F32>(b2l, tid); br[tid] = ldf<F32>(b2r, tid); }
    __syncthreads();
    int n = blockIdx.x * blockDim.x + tid;
    if (n >= N) return;
    float hv[32];
    #pragma unroll
    for (int c = 0; c < 32; ++c) hv[c] = b2f(hbuf[n * 32 + c]);
    float accl[16], accr[16];
    #pragma unroll
    for (int o = 0; o < 16; ++o) { accl[o] = bl[o]; accr[o] = br[o]; }
    #pragma unroll
    for (int c = 0; c < 32; ++c) {
        #pragma unroll
        for (int o = 0; o < 16; ++o) {
            accl[o] = fmaf(hv[c], wl[c * 16 + o], accl[o]);
            accr[o] = fmaf(hv[c], wr[c * 16 + o], accr[o]);
        }
    }
    #pragma unroll
    for (int o = 0; o < 16; ++o) {
        hbuf[n * 32 + o]      = f2b(accl[o]);   // h2l
        hbuf[n * 32 + 16 + o] = f2b(accr[o]);   // h2r
    }
}

__global__ __launch_bounds__(256) void node2_kernel(
    const int* __restrict__ flags, bf16* __restrict__ hbuf,
    const void* W2l, const void* b2l, const void* W2r, const void* b2r, int N) {
    __shared__ float wl[512], wr[512];
    if (flags[1]) node2_body<1>(hbuf, wl, wr, W2l, b2l, W2r, b2r, N);
    else          node2_body<0>(hbuf, wl, wr, W2l, b2l, W2r, b2r, N);
}

// ================= Layer-2 aggregation (r12 exact) =================

template<int F32, int P4>
__device__ void agg2_body(
    const int* __restrict__ rowptr, const void* __restrict__ csr,
    const bf16* __restrict__ h2,
    const void* We2, const void* att2, const void* bias2, const void* g2v, const void* beta2,
    void* __restrict__ out, int N) {
    int w0 = __builtin_amdgcn_readfirstlane((blockIdx.x * blockDim.x + threadIdx.x) >> 6);
    int NW = (gridDim.x * blockDim.x) >> 6;
    int lane = threadIdx.x & 63;
    int g = lane >> 4, t = lane & 15;

    float we = ldf<F32>(We2, t), at = ldf<F32>(att2, t);
    float bia = ldf<F32>(bias2, t), gg = ldf<F32>(g2v, t), bb = ldf<F32>(beta2, t);

    for (int n = w0; n < N; n += NW) {
        int beg = rowptr[n], end = rowptr[n + 1];
        float xr = b2f(h2[n * 32 + 16 + t]);

        float S = 0.f, A = 0.f;
        auto edge = [&](float v, float a) {
            float m = fmaf(a, we, v + xr);
            m = fmaxf(m, NEG_SLOPE * m);
            float p = sclamp(red16(m * at), 60.f);
            float e = __expf(p);
            S += e;
            A = fmaf(e, v, A);
        };
        int k = beg + g;
        for (; k + 4 < end; k += 8) {
            int s0, s1; float a0, a1;
            ldrec<P4>(csr, k, s0, a0);
            ldrec<P4>(csr, k + 4, s1, a1);
            float v0 = b2f(h2[s0 * 32 + t]);
            float v1 = b2f(h2[s1 * 32 + t]);
            edge(v0, a0);
            edge(v1, a1);
        }
        if (k < end) {
            int s0; float a0;
            ldrec<P4>(csr, k, s0, a0);
            edge(b2f(h2[s0 * 32 + t]), a0);
        }
        S += __shfl_xor(S, 16); S += __shfl_xor(S, 32);
        A += __shfl_xor(A, 16); A += __shfl_xor(A, 32);
        float val = A / (S + 1e-16f) + bia;

        float mu = red16(val) * (1.f / 16.f);
        float d = val - mu;
        float var = red16(d * d) * (1.f / 16.f);
        float y = fmaf(d * rsqrtf(var + LN_EPS), gg, bb);
        if (lane < 16) {
            if (F32) ((float*)out)[n * 16 + t] = y;
            else     ((bf16*)out)[n * 16 + t] = f2b(y);
        }
    }
}

template<int P4>
__global__ __launch_bounds__(256) void agg2_kernel(
    const int* __restrict__ flags,
    const int* __restrict__ rowptr, const void* __restrict__ csr,
    const bf16* __restrict__ h2,
    const void* We2, const void* att2, const void* bias2, const void* g2v, const void* beta2,
    void* __restrict__ out, int N) {
    if (flags[1]) agg2_body<1, P4>(rowptr, csr, h2, We2, att2, bias2, g2v, beta2, out, N);
    else          agg2_body<0, P4>(rowptr, csr, h2, We2, att2, bias2, g2v, beta2, out, N);
}

// ================= host =================

static inline size_t align256(size_t x) { return (x + 255) & ~size_t(255); }

extern "C" void kernel_launch(void* const* d_in, const int* in_sizes, int n_in,
                              void* d_out, int out_size, void* d_ws, size_t ws_size,
                              hipStream_t stream) {
    const void* x     = d_in[0];
    const int*  ei    = (const int*)d_in[1];
    const void* eattr = d_in[2];
    const void* W1l   = d_in[3];
    const void* b1l   = d_in[4];
    const void* W1r   = d_in[5];
    const void* b1r   = d_in[6];
    const void* We1   = d_in[7];
    const void* att1  = d_in[8];
    const void* bias1 = d_in[9];
    const void* g1    = d_in[10];
    const void* beta1 = d_in[11];
    const void* W2l   = d_in[12];
    const void* b2l   = d_in[13];
    const void* W2r   = d_in[14];
    const void* b2r   = d_in[15];
    const void* We2   = d_in[16];
    const void* att2  = d_in[17];
    const void* bias2 = d_in[18];
    const void* g2    = d_in[19];
    const void* beta2 = d_in[20];

    const int N = in_sizes[0] / 2;   // x is (N,2)
    const int E = in_sizes[2];       // edge_attr is (E,1)
    const int EB = (E + ACHUNK - 1) / ACHUNK;
    const int NB = (N + 255) >> 8;
    const bool p4 = (N <= 65536) && (EB <= EBMAX);

    char* ws = (char*)d_ws;
    size_t off = 0;
    int* flags  = (int*)(ws + off); off += align256(sizeof(int) * 2);
    int* cntm   = (int*)(ws + off); off += align256(sizeof(int) * (size_t)EB * 256);  // also bsum (fallback)
    int* locm   = (int*)(ws + off); off += align256(sizeof(int) * (size_t)EB * 256);
    int* btot   = (int*)(ws + off); off += align256(sizeof(int) * 256);
    int* rowptr = (int*)(ws + off); off += align256(sizeof(int) * (size_t)(N + 1));
    void* csr   = (void*)(ws + off); off += align256((p4 ? 4u : 8u) * (size_t)E);
    char* big   = (ws + off);
    // p4 layout inside big: binned4 | binnedb (both dead after passb); hbuf overlays.
    unsigned* binned4 = (unsigned*)big;
    unsigned char* binnedb = (unsigned char*)(big + align256(sizeof(unsigned) * (size_t)EB * ACHUNK));
    bf16* hbuf = (bf16*)big;

    if (p4) {
        bina1_kernel<<<EB, 256, 0, stream>>>(ei, eattr, (const unsigned short*)x,
                                             E, N, flags, binned4, binnedb, cntm, locm);
        sumb_kernel<<<NB, 256, 0, stream>>>(cntm, btot, EB, rowptr, N, E);
        passb_kernel<<<NB, 256, 0, stream>>>(binned4, binnedb, cntm, locm, btot,
                                             rowptr, (unsigned*)csr, N, EB, NB);
    } else {
        int* cnt = (int*)big;
        hbuf = (bf16*)(big + align256(sizeof(int) * (size_t)N));
        const int B = (N + SCAN_TILE - 1) / SCAN_TILE;
        hipMemsetAsync(cnt, 0, sizeof(int) * (size_t)N, stream);
        hist_kernel<<<(E + 255) / 256, 256, 0, stream>>>(ei, (const unsigned short*)x, E, N, flags, cnt);
        scan_partial<<<B, 256, 0, stream>>>(cnt, cntm, N);
        scan_final<<<B, 256, 0, stream>>>(cnt, rowptr, cntm, N, B);
        scatter_kernel<<<(E + 255) / 256, 256, 0, stream>>>(ei, eattr, E, N, flags, cnt, (uint2*)csr);
    }

    if (p4) agg1_kernel<1><<<2048, 256, 0, stream>>>(flags, rowptr, csr, x,
                                                     W1l, b1l, W1r, b1r, We1, att1,
                                                     bias1, g1, beta1, hbuf, N);
    else    agg1_kernel<0><<<2048, 256, 0, stream>>>(flags, rowptr, csr, x,
                                                     W1l, b1l, W1r, b1r, We1, att1,
                                                     bias1, g1, beta1, hbuf, N);

    node2_kernel<<<(N + 255) / 256, 256, 0, stream>>>(flags, hbuf, W2l, b2l, W2r, b2r, N);

    if (p4) agg2_kernel<1><<<2048, 256, 0, stream>>>(flags, rowptr, csr, hbuf,
                                                     We2, att2, bias2, g2, beta2, d_out, N);
    else    agg2_kernel<0><<<2048, 256, 0, stream>>>(flags, rowptr, csr, hbuf,
                                                     We2, att2, bias2, g2, beta2, d_out, N);
}